// Round 1
// baseline (2287.847 us; speedup 1.0000x reference)
//
#include <hip/hip_runtime.h>

typedef unsigned int uint;
typedef unsigned short ushort;

#define SCALE_ 0.17677669529663687f

__device__ inline float blo(uint u){ return __uint_as_float(u << 16); }
__device__ inline float bhi(uint u){ return __uint_as_float(u & 0xffff0000u); }
__device__ inline ushort f2bf(float f){
  uint u = __float_as_uint(f);
  return (ushort)((u + 0x7fffu + ((u >> 16) & 1u)) >> 16);
}
__device__ inline float bf2f(ushort h){ return __uint_as_float(((uint)h) << 16); }

// ---------------------------------------------------------------------------
// Kernel 1: fused LN1 + shift + window partition + QKV + attention + proj +
// residual.  One block per window (B*64 = 4096 blocks), 256 threads.
// ---------------------------------------------------------------------------
__global__ __launch_bounds__(256) void attn_kernel(
    const float* __restrict__ x, const float* __restrict__ g1, const float* __restrict__ b1,
    const float* __restrict__ qkv_w, const float* __restrict__ qkv_b,
    const float* __restrict__ rpb, const float* __restrict__ proj_w,
    const float* __restrict__ proj_b, float* __restrict__ x_new)
{
  // LDS: 25088 (xw fp32, aliased later by scores fp32 [49][52] + out bf16 [49][128])
  //      + 3 * 49*132*2 (q,k,v bf16, pad 132 to break bank conflicts) = 63896 B
  __shared__ __align__(16) float xw_region[6272];
  __shared__ __align__(16) ushort qb[49*132];
  __shared__ __align__(16) ushort kb[49*132];
  __shared__ __align__(16) ushort vb[49*132];

  float*  xwf = xw_region;                    // phase 1-2
  float*  scf = xw_region;                    // phase 3 (scores, 2544 floats)
  ushort* oa  = (ushort*)(xw_region + 2548);  // phase 3-4 (attn out bf16, 6272 ushorts)

  const int tid  = threadIdx.x;
  const int wave = tid >> 6, lane = tid & 63;
  const int blk  = blockIdx.x;
  const int b    = blk >> 6, wi = blk & 63;
  const int wr   = wi >> 3,  wc = wi & 7;
  const float* xb = x + (size_t)b * (3136 * 128);

  // ---- P1: gather (shifted) + LayerNorm1 -> xwf[49][128] fp32 ----
  for (int n = wave; n < 49; n += 4) {
    int tr = n / 7, tcc = n - tr * 7;
    int r = (wr * 7 + tr + 3) % 56;
    int c = (wc * 7 + tcc + 3) % 56;
    const float* row = xb + (size_t)(r * 56 + c) * 128;
    float2 v = *(const float2*)(row + (lane << 1));
    float s  = v.x + v.y;
    float s2 = v.x * v.x + v.y * v.y;
#pragma unroll
    for (int off = 32; off; off >>= 1) {
      s  += __shfl_xor(s, off);
      s2 += __shfl_xor(s2, off);
    }
    float mean = s * 0.0078125f;
    float var  = s2 * 0.0078125f - mean * mean;
    float rsig = rsqrtf(var + 1e-5f);
    int c0 = lane << 1;
    float2 gg = *(const float2*)(g1 + c0);
    float2 bb = *(const float2*)(b1 + c0);
    float2 res;
    res.x = (v.x - mean) * rsig * gg.x + bb.x;
    res.y = (v.y - mean) * rsig * gg.y + bb.y;
    *(float2*)&xwf[n * 128 + c0] = res;
  }
  __syncthreads();

  // ---- P2: QKV.  thread -> (channel o = tid&127, token-half = tid>>7). ----
  {
    const int o    = tid & 127;
    const int half = tid >> 7;           // wave-uniform
    const int nlo  = half ? 25 : 0;
    const int ncnt = half ? 24 : 25;
    float aq[25], ak[25], av[25];
#pragma unroll
    for (int i = 0; i < 25; ++i) { aq[i] = 0.f; ak[i] = 0.f; av[i] = 0.f; }
    const float* wq = qkv_w + (size_t)o * 128;
    const float* wk = qkv_w + (size_t)(o + 128) * 128;
    const float* wv = qkv_w + (size_t)(o + 256) * 128;
    for (int c = 0; c < 128; c += 4) {
      float4 q4 = *(const float4*)(wq + c);
      float4 k4 = *(const float4*)(wk + c);
      float4 v4 = *(const float4*)(wv + c);
#pragma unroll
      for (int nn = 0; nn < 25; ++nn) {
        if (nn < ncnt) {
          float4 xv = *(const float4*)&xwf[(nlo + nn) * 128 + c];
          aq[nn] += xv.x * q4.x + xv.y * q4.y + xv.z * q4.z + xv.w * q4.w;
          ak[nn] += xv.x * k4.x + xv.y * k4.y + xv.z * k4.z + xv.w * k4.w;
          av[nn] += xv.x * v4.x + xv.y * v4.y + xv.z * v4.z + xv.w * v4.w;
        }
      }
    }
    const float bq = qkv_b[o], bk = qkv_b[o + 128], bv = qkv_b[o + 256];
#pragma unroll
    for (int nn = 0; nn < 25; ++nn) {
      if (nn < ncnt) {
        int n = nlo + nn;
        qb[n * 132 + o] = f2bf((aq[nn] + bq) * SCALE_);
        kb[n * 132 + o] = f2bf(ak[nn] + bk);
        vb[n * 132 + o] = f2bf(av[nn] + bv);
      }
    }
  }
  __syncthreads();

  // ---- P3: per-head scores + softmax + PV ----
  for (int h = 0; h < 4; ++h) {
    // scores
    for (int idx = tid; idx < 2401; idx += 256) {
      int i = idx / 49, j = idx - i * 49;
      const ushort* qr = qb + i * 132 + h * 32;
      const ushort* kr = kb + j * 132 + h * 32;
      float acc = 0.f;
#pragma unroll
      for (int d = 0; d < 32; d += 4) {
        uint2 uq = *(const uint2*)(qr + d);
        uint2 uk = *(const uint2*)(kr + d);
        acc += blo(uq.x) * blo(uk.x) + bhi(uq.x) * bhi(uk.x)
             + blo(uq.y) * blo(uk.y) + bhi(uq.y) * bhi(uk.y);
      }
      int ri = i / 7, ci = i - ri * 7;
      int rj = j / 7, cj = j - rj * 7;
      int rel = (ri - rj + 6) * 13 + (ci - cj + 6);
      acc += rpb[rel * 4 + h];
      // shift mask (regions in shifted coords: [0,49)[49,53)[53,56))
      int ai = wr * 7 + ri, bi = wc * 7 + ci;
      int aj = wr * 7 + rj, bj = wc * 7 + cj;
      int regi = (ai < 49 ? 0 : (ai < 53 ? 1 : 2)) * 3 + (bi < 49 ? 0 : (bi < 53 ? 1 : 2));
      int regj = (aj < 49 ? 0 : (aj < 53 ? 1 : 2)) * 3 + (bj < 49 ? 0 : (bj < 53 ? 1 : 2));
      if (regi != regj) acc -= 100.f;
      scf[i * 52 + j] = acc;
    }
    __syncthreads();
    // softmax per row (wave-parallel, lane = column)
    for (int i = wave; i < 49; i += 4) {
      float v = (lane < 49) ? scf[i * 52 + lane] : -3.4e38f;
      float m = v;
#pragma unroll
      for (int off = 32; off; off >>= 1) m = fmaxf(m, __shfl_xor(m, off));
      float e = (lane < 49) ? __expf(v - m) : 0.f;
      float s = e;
#pragma unroll
      for (int off = 32; off; off >>= 1) s += __shfl_xor(s, off);
      if (lane < 49) scf[i * 52 + lane] = e / s;
    }
    __syncthreads();
    // PV: out[i][h*32 + 2*d2 .. +1]
    for (int idx = tid; idx < 49 * 16; idx += 256) {
      int i = idx >> 4, d2 = idx & 15;
      const ushort* vcol = vb + h * 32 + (d2 << 1);
      float a0 = 0.f, a1 = 0.f;
      for (int j = 0; j < 49; ++j) {
        float p = scf[i * 52 + j];
        uint u = *(const uint*)(vcol + j * 132);
        a0 += p * blo(u);
        a1 += p * bhi(u);
      }
      uint pk = (uint)f2bf(a0) | ((uint)f2bf(a1) << 16);
      *(uint*)&oa[i * 128 + h * 32 + (d2 << 1)] = pk;
    }
    __syncthreads();
  }

  // ---- P4: proj + reverse shift scatter + residual ----
  {
    const int o    = tid & 127;
    const int half = tid >> 7;
    const int nlo  = half ? 25 : 0;
    const int ncnt = half ? 24 : 25;
    float acc[25];
#pragma unroll
    for (int i = 0; i < 25; ++i) acc[i] = 0.f;
    const float* wrow = proj_w + (size_t)o * 128;
    for (int c = 0; c < 128; c += 4) {
      float4 w4 = *(const float4*)(wrow + c);
#pragma unroll
      for (int nn = 0; nn < 25; ++nn) {
        if (nn < ncnt) {
          uint2 u = *(const uint2*)&oa[(nlo + nn) * 128 + c];
          acc[nn] += blo(u.x) * w4.x + bhi(u.x) * w4.y
                   + blo(u.y) * w4.z + bhi(u.y) * w4.w;
        }
      }
    }
    const float pb = proj_b[o];
#pragma unroll
    for (int nn = 0; nn < 25; ++nn) {
      if (nn < ncnt) {
        int n = nlo + nn;
        int tr2 = n / 7, tc2 = n - tr2 * 7;
        int r = (wr * 7 + tr2 + 3) % 56;
        int c = (wc * 7 + tc2 + 3) % 56;
        size_t off = ((size_t)b * 3136 + r * 56 + c) * 128 + o;
        x_new[off] = x[off] + acc[nn] + pb;
      }
    }
  }
}

// ---------------------------------------------------------------------------
// Kernel 2: per-row LayerNorm2 stats (mean, rsigma) of x_new
// ---------------------------------------------------------------------------
__global__ __launch_bounds__(256) void stats_kernel(const float* __restrict__ xn,
                                                    float2* __restrict__ st)
{
  int row  = (blockIdx.x << 2) + (threadIdx.x >> 6);
  int lane = threadIdx.x & 63;
  float2 v = *(const float2*)(xn + (size_t)row * 128 + (lane << 1));
  float s = v.x + v.y, s2 = v.x * v.x + v.y * v.y;
#pragma unroll
  for (int off = 32; off; off >>= 1) {
    s  += __shfl_xor(s, off);
    s2 += __shfl_xor(s2, off);
  }
  if (lane == 0) {
    float mean = s * 0.0078125f;
    float var  = s2 * 0.0078125f - mean * mean;
    st[row] = make_float2(mean, rsqrtf(var + 1e-5f));
  }
}

// ---------------------------------------------------------------------------
// Kernel 3: fc1 = gelu(LN2(x_new) @ fc1_w.T + fc1_b) -> hid (bf16)
// 64x64 tile, K=128.  LDS tiles stored k-major with XOR-4 swizzle.
// ---------------------------------------------------------------------------
__global__ __launch_bounds__(256) void fc1_kernel(
    const float* __restrict__ xn, const float2* __restrict__ st,
    const float* __restrict__ g2, const float* __restrict__ b2,
    const float* __restrict__ fw, const float* __restrict__ fb,
    ushort* __restrict__ hid)
{
  __shared__ __align__(16) float AT[8192];
  __shared__ __align__(16) float WT[8192];
  const int tid = threadIdx.x;
  const int tc = tid & 15, tr = tid >> 4;
  const int ct = blockIdx.x;
  const int rowbase = blockIdx.y << 6;

  for (int it = 0; it < 8; ++it) {
    int i = tid + (it << 8);
    int row = i >> 5, c = (i & 31) << 2;
    int rg = rowbase + row;
    float4 v  = *(const float4*)(xn + (size_t)rg * 128 + c);
    float2 s  = st[rg];
    float4 gg = *(const float4*)(g2 + c);
    float4 bb = *(const float4*)(b2 + c);
    int sw = (c & 15) << 2;
    AT[(c + 0) * 64 + (row ^ (sw + 0))]  = (v.x - s.x) * s.y * gg.x + bb.x;
    AT[(c + 1) * 64 + (row ^ (sw + 4))]  = (v.y - s.x) * s.y * gg.y + bb.y;
    AT[(c + 2) * 64 + (row ^ (sw + 8))]  = (v.z - s.x) * s.y * gg.z + bb.z;
    AT[(c + 3) * 64 + (row ^ (sw + 12))] = (v.w - s.x) * s.y * gg.w + bb.w;
  }
  for (int it = 0; it < 8; ++it) {
    int i = tid + (it << 8);
    int o = i >> 5, c = (i & 31) << 2;
    float4 v = *(const float4*)(fw + (size_t)(ct * 64 + o) * 128 + c);
    int sw = (c & 15) << 2;
    WT[(c + 0) * 64 + (o ^ (sw + 0))]  = v.x;
    WT[(c + 1) * 64 + (o ^ (sw + 4))]  = v.y;
    WT[(c + 2) * 64 + (o ^ (sw + 8))]  = v.z;
    WT[(c + 3) * 64 + (o ^ (sw + 12))] = v.w;
  }
  __syncthreads();

  float acc[4][4] = {};
#pragma unroll 8
  for (int kk = 0; kk < 128; ++kk) {
    int sw = (kk & 15) << 2;
    const float4 a = *(const float4*)&AT[kk * 64 + ((tr << 2) ^ sw)];
    const float4 w = *(const float4*)&WT[kk * 64 + ((tc << 2) ^ sw)];
    float avv[4] = {a.x, a.y, a.z, a.w};
    float wvv[4] = {w.x, w.y, w.z, w.w};
#pragma unroll
    for (int i = 0; i < 4; ++i)
#pragma unroll
      for (int j = 0; j < 4; ++j)
        acc[i][j] += avv[i] * wvv[j];
  }

  const int o0 = ct * 64 + (tc << 2);
  const float4 fb4 = *(const float4*)(fb + o0);
  float fbv[4] = {fb4.x, fb4.y, fb4.z, fb4.w};
#pragma unroll
  for (int i = 0; i < 4; ++i) {
    int rg = rowbase + (tr << 2) + i;
    ushort4 pk;
    float v0 = acc[i][0] + fbv[0]; v0 = 0.5f * v0 * (1.f + erff(v0 * 0.70710678f));
    float v1 = acc[i][1] + fbv[1]; v1 = 0.5f * v1 * (1.f + erff(v1 * 0.70710678f));
    float v2 = acc[i][2] + fbv[2]; v2 = 0.5f * v2 * (1.f + erff(v2 * 0.70710678f));
    float v3 = acc[i][3] + fbv[3]; v3 = 0.5f * v3 * (1.f + erff(v3 * 0.70710678f));
    pk.x = f2bf(v0); pk.y = f2bf(v1); pk.z = f2bf(v2); pk.w = f2bf(v3);
    *(ushort4*)&hid[(size_t)rg * 512 + o0] = pk;
  }
}

// ---------------------------------------------------------------------------
// Kernel 4: fc2: out = x_new + (hid @ fc2_w.T + fc2_b).   64x64 tile, K=512.
// ---------------------------------------------------------------------------
__global__ __launch_bounds__(256) void fc2_kernel(
    const ushort* __restrict__ hid, const float* __restrict__ fw,
    const float* __restrict__ fb, const float* __restrict__ xn,
    float* __restrict__ out)
{
  __shared__ __align__(16) float AT[8192];
  __shared__ __align__(16) float WT[8192];
  const int tid = threadIdx.x;
  const int tc = tid & 15, tr = tid >> 4;
  const int ct = blockIdx.x;
  const int rowbase = blockIdx.y << 6;

  float acc[4][4] = {};
  for (int ck = 0; ck < 4; ++ck) {
    if (ck) __syncthreads();
    for (int it = 0; it < 32; ++it) {
      int i = tid + (it << 8);
      int row = i >> 7, c = i & 127;
      float v = bf2f(hid[(size_t)(rowbase + row) * 512 + (ck << 7) + c]);
      AT[c * 64 + (row ^ (((c & 15) << 2)))] = v;
    }
    for (int it = 0; it < 8; ++it) {
      int i = tid + (it << 8);
      int o = i >> 5, c = (i & 31) << 2;
      float4 v = *(const float4*)(fw + (size_t)(ct * 64 + o) * 512 + (ck << 7) + c);
      int sw = (c & 15) << 2;
      WT[(c + 0) * 64 + (o ^ (sw + 0))]  = v.x;
      WT[(c + 1) * 64 + (o ^ (sw + 4))]  = v.y;
      WT[(c + 2) * 64 + (o ^ (sw + 8))]  = v.z;
      WT[(c + 3) * 64 + (o ^ (sw + 12))] = v.w;
    }
    __syncthreads();
#pragma unroll 8
    for (int kk = 0; kk < 128; ++kk) {
      int sw = (kk & 15) << 2;
      const float4 a = *(const float4*)&AT[kk * 64 + ((tr << 2) ^ sw)];
      const float4 w = *(const float4*)&WT[kk * 64 + ((tc << 2) ^ sw)];
      float avv[4] = {a.x, a.y, a.z, a.w};
      float wvv[4] = {w.x, w.y, w.z, w.w};
#pragma unroll
      for (int i = 0; i < 4; ++i)
#pragma unroll
        for (int j = 0; j < 4; ++j)
          acc[i][j] += avv[i] * wvv[j];
    }
  }

  const int o0 = ct * 64 + (tc << 2);
  const float4 fb4 = *(const float4*)(fb + o0);
#pragma unroll
  for (int i = 0; i < 4; ++i) {
    int rg = rowbase + (tr << 2) + i;
    float4 r = *(const float4*)(xn + (size_t)rg * 128 + o0);
    float4 ov;
    ov.x = r.x + acc[i][0] + fb4.x;
    ov.y = r.y + acc[i][1] + fb4.y;
    ov.z = r.z + acc[i][2] + fb4.z;
    ov.w = r.w + acc[i][3] + fb4.w;
    *(float4*)(out + (size_t)rg * 128 + o0) = ov;
  }
}

// ---------------------------------------------------------------------------
extern "C" void kernel_launch(void* const* d_in, const int* in_sizes, int n_in,
                              void* d_out, int out_size, void* d_ws, size_t ws_size,
                              hipStream_t stream)
{
  const float* x      = (const float*)d_in[0];
  const float* g1     = (const float*)d_in[1];
  const float* b1     = (const float*)d_in[2];
  const float* qkv_w  = (const float*)d_in[3];
  const float* qkv_b  = (const float*)d_in[4];
  const float* rpb    = (const float*)d_in[5];
  const float* proj_w = (const float*)d_in[6];
  const float* proj_b = (const float*)d_in[7];
  const float* g2     = (const float*)d_in[8];
  const float* b2     = (const float*)d_in[9];
  const float* fc1_w  = (const float*)d_in[10];
  const float* fc1_b  = (const float*)d_in[11];
  const float* fc2_w  = (const float*)d_in[12];
  const float* fc2_b  = (const float*)d_in[13];

  float* out   = (float*)d_out;
  float* x_new = out;  // attn-path result lives in d_out (fully overwritten later)
  float2* st   = (float2*)d_ws;                              // 200704 * 8 B
  ushort* hid  = (ushort*)((char*)d_ws + 1605632);           // 200704*512*2 B

  attn_kernel<<<4096, 256, 0, stream>>>(x, g1, b1, qkv_w, qkv_b, rpb,
                                        proj_w, proj_b, x_new);
  stats_kernel<<<50176, 256, 0, stream>>>(x_new, st);
  fc1_kernel<<<dim3(8, 3136), 256, 0, stream>>>(x_new, st, g2, b2,
                                                fc1_w, fc1_b, hid);
  fc2_kernel<<<dim3(2, 3136), 256, 0, stream>>>(hid, fc2_w, fc2_b, x_new, out);
}

// Round 2
// 828.658 us; speedup vs baseline: 2.7609x; 2.7609x over previous
//
#include <hip/hip_runtime.h>

typedef unsigned int uint;
typedef unsigned short ushort;
using short8 = __attribute__((ext_vector_type(8))) short;
using f32x4  = __attribute__((ext_vector_type(4))) float;

#define SCALE_ 0.17677669529663687f
#define MFMA(a,b,c) __builtin_amdgcn_mfma_f32_16x16x32_bf16(a,b,c,0,0,0)

__device__ inline ushort f2bf(float f){
  uint u = __float_as_uint(f);
  return (ushort)((u + 0x7fffu + ((u >> 16) & 1u)) >> 16);
}

// ---------------------------------------------------------------------------
// prep: bf16 weights (SCALE folded into q), scaled qkv bias, bias+mask table
// T[cls][h][j][i] (fp32, 64x64 padded; pad = -30000 so padding self-masks).
// ---------------------------------------------------------------------------
__global__ __launch_bounds__(256) void prep_kernel(
    const float* __restrict__ qkv_w, const float* __restrict__ qkv_b,
    const float* __restrict__ rpb, const float* __restrict__ proj_w,
    const float* __restrict__ fc1_w, const float* __restrict__ fc2_w,
    ushort* __restrict__ qkv_wb, float* __restrict__ qkv_bs,
    ushort* __restrict__ proj_wb, ushort* __restrict__ fc1_wb,
    ushort* __restrict__ fc2_wb, float* __restrict__ T)
{
  int i = blockIdx.x * 256 + threadIdx.x;           // 0..65535
  if (i < 49152) qkv_wb[i] = f2bf(qkv_w[i] * (i < 16384 ? SCALE_ : 1.f));
  if (i < 16384) proj_wb[i] = f2bf(proj_w[i]);
  if (i < 65536) { fc1_wb[i] = f2bf(fc1_w[i]); fc2_wb[i] = f2bf(fc2_w[i]); }
  if (i < 384)   qkv_bs[i] = qkv_b[i] * (i < 128 ? SCALE_ : 1.f);
  if (i < 65536) {
    int cls = i >> 14, h = (i >> 12) & 3, j = (i >> 6) & 63, ii = i & 63;
    float val = -30000.f;
    if (ii < 49 && j < 49) {
      int ri = ii / 7, ci = ii - ri * 7, rj = j / 7, cj = j - rj * 7;
      val = rpb[((ri - rj + 6) * 13 + (ci - cj + 6)) * 4 + h];
      int er = cls >> 1, ec = cls & 1;
      int regi = (er ? (ri < 4 ? 1 : 2) : 0) * 3 + (ec ? (ci < 4 ? 1 : 2) : 0);
      int regj = (er ? (rj < 4 ? 1 : 2) : 0) * 3 + (ec ? (cj < 4 ? 1 : 2) : 0);
      if (regi != regj) val -= 100.f;
    }
    T[i] = val;
  }
}

// ---------------------------------------------------------------------------
// attn: LN1 + shift + QKV(MFMA) + scores(MFMA)+bias+in-reg softmax + PV(MFMA)
// + proj(MFMA) + residual scatter. 1 block = 1 window (padded 49->64 tokens).
// ---------------------------------------------------------------------------
__global__ __launch_bounds__(256) void attn_kernel(
    const float* __restrict__ x, const float* __restrict__ g1, const float* __restrict__ b1,
    const ushort* __restrict__ qkv_wb, const float* __restrict__ qkv_bs,
    const float* __restrict__ T, const ushort* __restrict__ proj_wb,
    const float* __restrict__ proj_b, float* __restrict__ x_new)
{
  // LDS map (bytes): xwb[64][136] @0 (17408), qb[64][136] @17408, pad @34816,
  // kb[64][136] @36864 (aliased by oa), vbt[128][72] @54272; P[4][64][72]
  // aliases @0..36863. Row strides 272B/144B == 16 mod 32 -> 2-way banks.
  __shared__ __align__(16) char smem[72704];
  ushort* xwb = (ushort*)smem;
  ushort* qb  = (ushort*)(smem + 17408);
  ushort* kb  = (ushort*)(smem + 36864);
  ushort* vbt = (ushort*)(smem + 54272);
  ushort* Pl  = (ushort*)smem;
  ushort* oa  = kb;

  const int tid = threadIdx.x;
  const int w = tid >> 6, lane = tid & 63;
  const int g = lane >> 4, li = lane & 15;
  const int blk = blockIdx.x;
  const int b = blk >> 6, wi = blk & 63;
  const int wr = wi >> 3, wc = wi & 7;
  const float* xb = x + (size_t)b * (3136 * 128);
  const f32x4 zf = {0.f, 0.f, 0.f, 0.f};

  // ---- P1: shifted gather + LN1 -> xwb bf16; zero pad rows 49..63 ----
  for (int n = w; n < 49; n += 4) {
    int tr = n / 7, tc = n - tr * 7;
    int r = (wr * 7 + tr + 3) % 56;
    int c = (wc * 7 + tc + 3) % 56;
    const float* row = xb + (size_t)(r * 56 + c) * 128;
    float2 v = *(const float2*)(row + (lane << 1));
    float s = v.x + v.y, s2 = v.x * v.x + v.y * v.y;
#pragma unroll
    for (int off = 32; off; off >>= 1) { s += __shfl_xor(s, off); s2 += __shfl_xor(s2, off); }
    float mean = s * 0.0078125f;
    float rsig = rsqrtf(s2 * 0.0078125f - mean * mean + 1e-5f);
    int c0 = lane << 1;
    float2 gg = *(const float2*)(g1 + c0);
    float2 bb = *(const float2*)(b1 + c0);
    uint pk = (uint)f2bf((v.x - mean) * rsig * gg.x + bb.x)
            | ((uint)f2bf((v.y - mean) * rsig * gg.y + bb.y) << 16);
    *(uint*)&xwb[n * 136 + c0] = pk;
  }
  for (int i = tid; i < 960; i += 256) {
    int rr = 49 + (i >> 6), cc = (i & 63) << 1;
    *(uint*)&xwb[rr * 136 + cc] = 0;
  }
  __syncthreads();

  // ---- P2: QKV via MFMA. wave w owns output cols [w*96, w*96+96) ----
  {
    f32x4 acc[6][4];
#pragma unroll
    for (int nf = 0; nf < 6; ++nf)
#pragma unroll
      for (int m = 0; m < 4; ++m) acc[nf][m] = zf;
#pragma unroll
    for (int kt = 0; kt < 4; ++kt) {
      short8 a[4], bf[6];
#pragma unroll
      for (int m = 0; m < 4; ++m)
        a[m] = *(const short8*)&xwb[(m * 16 + li) * 136 + kt * 32 + g * 8];
#pragma unroll
      for (int nf = 0; nf < 6; ++nf)
        bf[nf] = *(const short8*)(qkv_wb + (w * 96 + nf * 16 + li) * 128 + kt * 32 + g * 8);
#pragma unroll
      for (int nf = 0; nf < 6; ++nf)
#pragma unroll
        for (int m = 0; m < 4; ++m)
          acc[nf][m] = MFMA(a[m], bf[nf], acc[nf][m]);
    }
#pragma unroll
    for (int nf = 0; nf < 6; ++nf) {
      int base = w * 96 + nf * 16;
      int part = base >> 7;
      int c0 = (base & 127) + li;
      float bias = qkv_bs[base + li];
#pragma unroll
      for (int m = 0; m < 4; ++m)
#pragma unroll
        for (int r = 0; r < 4; ++r) {
          int tok = m * 16 + g * 4 + r;
          ushort hv = f2bf(acc[nf][m][r] + bias);
          if (part == 0)      qb[tok * 136 + c0] = hv;
          else if (part == 1) kb[tok * 136 + c0] = hv;
          else                vbt[c0 * 72 + tok] = hv;   // V transposed
        }
    }
  }
  __syncthreads();

  // ---- P3: per-wave head: scores MFMA + bias table + in-reg softmax + PV ----
  {
    const int h = w;
    short8 qf[4], kf[4];
#pragma unroll
    for (int m = 0; m < 4; ++m)
      qf[m] = *(const short8*)&qb[(m * 16 + li) * 136 + h * 32 + g * 8];
#pragma unroll
    for (int n = 0; n < 4; ++n)
      kf[n] = *(const short8*)&kb[(n * 16 + li) * 136 + h * 32 + g * 8];
    f32x4 s[4][4];
#pragma unroll
    for (int m = 0; m < 4; ++m)
#pragma unroll
      for (int n = 0; n < 4; ++n)
        s[m][n] = MFMA(qf[m], kf[n], zf);
    const int cls = ((wr == 7) ? 2 : 0) | ((wc == 7) ? 1 : 0);
    const float* Tb = T + ((cls * 4 + h) << 12);
#pragma unroll
    for (int m = 0; m < 4; ++m)
#pragma unroll
      for (int n = 0; n < 4; ++n) {
        f32x4 tv = *(const f32x4*)(Tb + (n * 16 + li) * 64 + m * 16 + g * 4);
        s[m][n] += tv;
      }
    // softmax: row = (m, g, r); cols spread over n (in-thread) x 16 lanes
#pragma unroll
    for (int m = 0; m < 4; ++m) {
      float rmax[4], rsum[4];
#pragma unroll
      for (int r = 0; r < 4; ++r)
        rmax[r] = fmaxf(fmaxf(s[m][0][r], s[m][1][r]), fmaxf(s[m][2][r], s[m][3][r]));
#pragma unroll
      for (int st = 1; st < 16; st <<= 1)
#pragma unroll
        for (int r = 0; r < 4; ++r)
          rmax[r] = fmaxf(rmax[r], __shfl_xor(rmax[r], st));
#pragma unroll
      for (int r = 0; r < 4; ++r) rsum[r] = 0.f;
#pragma unroll
      for (int n = 0; n < 4; ++n)
#pragma unroll
        for (int r = 0; r < 4; ++r) {
          float e = __expf(s[m][n][r] - rmax[r]);
          s[m][n][r] = e; rsum[r] += e;
        }
#pragma unroll
      for (int st = 1; st < 16; st <<= 1)
#pragma unroll
        for (int r = 0; r < 4; ++r)
          rsum[r] += __shfl_xor(rsum[r], st);
#pragma unroll
      for (int r = 0; r < 4; ++r) rsum[r] = 1.f / rsum[r];
#pragma unroll
      for (int n = 0; n < 4; ++n)
#pragma unroll
        for (int r = 0; r < 4; ++r)
          s[m][n][r] *= rsum[r];
    }
    __syncthreads();   // protects P alias over xwb/qb and oa alias over kb
    ushort* Ph = Pl + h * 4608;
#pragma unroll
    for (int m = 0; m < 4; ++m)
#pragma unroll
      for (int n = 0; n < 4; ++n)
#pragma unroll
        for (int r = 0; r < 4; ++r)
          Ph[(m * 16 + g * 4 + r) * 72 + n * 16 + li] = f2bf(s[m][n][r]);
    // PV
    f32x4 o[4][2];
#pragma unroll
    for (int m = 0; m < 4; ++m) { o[m][0] = zf; o[m][1] = zf; }
#pragma unroll
    for (int kt = 0; kt < 2; ++kt) {
      short8 pa[4], vf[2];
#pragma unroll
      for (int m = 0; m < 4; ++m)
        pa[m] = *(const short8*)&Ph[(m * 16 + li) * 72 + kt * 32 + g * 8];
#pragma unroll
      for (int nf = 0; nf < 2; ++nf)
        vf[nf] = *(const short8*)&vbt[(h * 32 + nf * 16 + li) * 72 + kt * 32 + g * 8];
#pragma unroll
      for (int m = 0; m < 4; ++m)
#pragma unroll
        for (int nf = 0; nf < 2; ++nf)
          o[m][nf] = MFMA(pa[m], vf[nf], o[m][nf]);
    }
#pragma unroll
    for (int m = 0; m < 4; ++m)
#pragma unroll
      for (int nf = 0; nf < 2; ++nf)
#pragma unroll
        for (int r = 0; r < 4; ++r)
          oa[(m * 16 + g * 4 + r) * 136 + h * 32 + nf * 16 + li] = f2bf(o[m][nf][r]);
  }
  __syncthreads();

  // ---- P4: proj via MFMA (wave w owns cols [w*32, w*32+32)) + scatter ----
  {
    f32x4 pacc[2][4];
#pragma unroll
    for (int nf = 0; nf < 2; ++nf)
#pragma unroll
      for (int m = 0; m < 4; ++m) pacc[nf][m] = zf;
#pragma unroll
    for (int kt = 0; kt < 4; ++kt) {
      short8 a[4], bf2[2];
#pragma unroll
      for (int m = 0; m < 4; ++m)
        a[m] = *(const short8*)&oa[(m * 16 + li) * 136 + kt * 32 + g * 8];
#pragma unroll
      for (int nf = 0; nf < 2; ++nf)
        bf2[nf] = *(const short8*)(proj_wb + (w * 32 + nf * 16 + li) * 128 + kt * 32 + g * 8);
#pragma unroll
      for (int nf = 0; nf < 2; ++nf)
#pragma unroll
        for (int m = 0; m < 4; ++m)
          pacc[nf][m] = MFMA(a[m], bf2[nf], pacc[nf][m]);
    }
#pragma unroll
    for (int nf = 0; nf < 2; ++nf) {
      int col = w * 32 + nf * 16 + li;
      float pb = proj_b[col];
#pragma unroll
      for (int m = 0; m < 4; ++m)
#pragma unroll
        for (int r = 0; r < 4; ++r) {
          int tok = m * 16 + g * 4 + r;
          if (tok < 49) {
            int tr2 = tok / 7, tc2 = tok - tr2 * 7;
            int rr = (wr * 7 + tr2 + 3) % 56;
            int cc = (wc * 7 + tc2 + 3) % 56;
            size_t off = ((size_t)b * 3136 + rr * 56 + cc) * 128 + col;
            x_new[off] = x[off] + pacc[nf][m][r] + pb;
          }
        }
    }
  }
}

// ---------------------------------------------------------------------------
// fc1: hid = gelu(LN2(x_new) @ fc1_w^T + b). 128x128 tile, LN2 fused in
// A-staging, chunk-XOR swizzled LDS, bf16 MFMA, LDS-repacked bf16 store.
// ---------------------------------------------------------------------------
__global__ __launch_bounds__(256) void fc1_kernel(
    const float* __restrict__ xn, const float* __restrict__ g2, const float* __restrict__ b2,
    const ushort* __restrict__ fw, const float* __restrict__ fb, ushort* __restrict__ hid)
{
  __shared__ __align__(16) ushort Ab[16384];
  __shared__ __align__(16) ushort Bb[16384];
  const int tid = threadIdx.x, lane = tid & 63, w = tid >> 6;
  const int g = lane >> 4, li = lane & 15;
  const size_t rowbase = (size_t)blockIdx.y * 128;
  const int ct = blockIdx.x;

  { // A staging + fused LN2 (thread: row=tid>>1, half=tid&1)
    int row = tid >> 1, hh = tid & 1;
    const float* src = xn + (rowbase + row) * 128 + hh * 64;
    float4 v[16];
    float s = 0.f, s2 = 0.f;
#pragma unroll
    for (int it = 0; it < 16; ++it) {
      v[it] = *(const float4*)(src + it * 4);
      s  += v[it].x + v[it].y + v[it].z + v[it].w;
      s2 += v[it].x * v[it].x + v[it].y * v[it].y + v[it].z * v[it].z + v[it].w * v[it].w;
    }
    s += __shfl_xor(s, 1); s2 += __shfl_xor(s2, 1);
    float mean = s * 0.0078125f;
    float rsig = rsqrtf(s2 * 0.0078125f - mean * mean + 1e-5f);
#pragma unroll
    for (int c2 = 0; c2 < 8; ++c2) {
      int cbase = hh * 64 + c2 * 8;
      float4 va = v[c2 * 2], vb = v[c2 * 2 + 1];
      float4 ga = *(const float4*)(g2 + cbase), gb = *(const float4*)(g2 + cbase + 4);
      float4 ba = *(const float4*)(b2 + cbase), bb = *(const float4*)(b2 + cbase + 4);
      uint4 pk;
      pk.x = (uint)f2bf((va.x - mean) * rsig * ga.x + ba.x) | ((uint)f2bf((va.y - mean) * rsig * ga.y + ba.y) << 16);
      pk.y = (uint)f2bf((va.z - mean) * rsig * ga.z + ba.z) | ((uint)f2bf((va.w - mean) * rsig * ga.w + ba.w) << 16);
      pk.z = (uint)f2bf((vb.x - mean) * rsig * gb.x + bb.x) | ((uint)f2bf((vb.y - mean) * rsig * gb.y + bb.y) << 16);
      pk.w = (uint)f2bf((vb.z - mean) * rsig * gb.z + bb.z) | ((uint)f2bf((vb.w - mean) * rsig * gb.w + bb.w) << 16);
      int ch = hh * 8 + c2;
      *(uint4*)&Ab[row * 128 + ((ch ^ (row & 7)) * 8)] = pk;
    }
  }
#pragma unroll
  for (int it = 0; it < 8; ++it) {
    int gi = it * 256 + tid, row = gi >> 4, ch = gi & 15;
    uint4 d = *(const uint4*)(fw + (size_t)(ct * 128 + row) * 128 + ch * 8);
    *(uint4*)&Bb[row * 128 + ((ch ^ (row & 7)) * 8)] = d;
  }
  __syncthreads();

  const int wr = w >> 1, wc = w & 1;
  f32x4 acc[4][4];
  const f32x4 zf = {0.f, 0.f, 0.f, 0.f};
#pragma unroll
  for (int m = 0; m < 4; ++m)
#pragma unroll
    for (int n = 0; n < 4; ++n) acc[m][n] = zf;
#pragma unroll
  for (int kt = 0; kt < 4; ++kt) {
    short8 a[4], bf[4];
#pragma unroll
    for (int m = 0; m < 4; ++m) {
      int row = wr * 64 + m * 16 + li;
      a[m] = *(const short8*)&Ab[row * 128 + (((kt * 4 + g) ^ (row & 7)) * 8)];
    }
#pragma unroll
    for (int n = 0; n < 4; ++n) {
      int row = wc * 64 + n * 16 + li;
      bf[n] = *(const short8*)&Bb[row * 128 + (((kt * 4 + g) ^ (row & 7)) * 8)];
    }
#pragma unroll
    for (int m = 0; m < 4; ++m)
#pragma unroll
      for (int n = 0; n < 4; ++n)
        acc[m][n] = MFMA(a[m], bf[n], acc[m][n]);
  }
  __syncthreads();
#pragma unroll
  for (int n = 0; n < 4; ++n) {
    int col_l = wc * 64 + n * 16 + li;
    float bias = fb[ct * 128 + col_l];
#pragma unroll
    for (int m = 0; m < 4; ++m)
#pragma unroll
      for (int r = 0; r < 4; ++r) {
        float vv = acc[m][n][r] + bias;
        vv = 0.5f * vv * (1.f + erff(vv * 0.70710678f));
        int row_l = wr * 64 + m * 16 + g * 4 + r;
        Ab[row_l * 128 + (col_l ^ ((row_l & 7) << 3))] = f2bf(vv);
      }
  }
  __syncthreads();
#pragma unroll
  for (int it = 0; it < 8; ++it) {
    int gi = it * 256 + tid, row = gi >> 4, ch = gi & 15;
    uint4 d = *(const uint4*)&Ab[row * 128 + ((ch ^ (row & 7)) * 8)];
    *(uint4*)&hid[(rowbase + row) * 512 + ct * 128 + ch * 8] = d;
  }
}

// ---------------------------------------------------------------------------
// fc2: out = x_new + hid @ fc2_w^T + b (in-place on d_out). 128x128 tile,
// K-loop of 4, bf16 MFMA, fp32 LDS repack for coalesced residual epilogue.
// ---------------------------------------------------------------------------
__global__ __launch_bounds__(256) void fc2_kernel(
    const ushort* __restrict__ hid, const ushort* __restrict__ fw,
    const float* __restrict__ fb, float* __restrict__ out)
{
  __shared__ __align__(16) char smem[65536];
  ushort* Ab = (ushort*)smem;
  ushort* Bb = (ushort*)(smem + 32768);
  float*  Rp = (float*)smem;
  const int tid = threadIdx.x, lane = tid & 63, w = tid >> 6;
  const int g = lane >> 4, li = lane & 15;
  const size_t rowbase = (size_t)blockIdx.x * 128;
  const int wr = w >> 1, wc = w & 1;

  f32x4 acc[4][4];
  const f32x4 zf = {0.f, 0.f, 0.f, 0.f};
#pragma unroll
  for (int m = 0; m < 4; ++m)
#pragma unroll
    for (int n = 0; n < 4; ++n) acc[m][n] = zf;

  for (int ck = 0; ck < 4; ++ck) {
    if (ck) __syncthreads();
#pragma unroll
    for (int it = 0; it < 8; ++it) {
      int gi = it * 256 + tid, row = gi >> 4, ch = gi & 15;
      uint4 d = *(const uint4*)(hid + (rowbase + row) * 512 + ck * 128 + ch * 8);
      *(uint4*)&Ab[row * 128 + ((ch ^ (row & 7)) * 8)] = d;
      uint4 e = *(const uint4*)(fw + (size_t)row * 512 + ck * 128 + ch * 8);
      *(uint4*)&Bb[row * 128 + ((ch ^ (row & 7)) * 8)] = e;
    }
    __syncthreads();
#pragma unroll
    for (int kt = 0; kt < 4; ++kt) {
      short8 a[4], bf[4];
#pragma unroll
      for (int m = 0; m < 4; ++m) {
        int row = wr * 64 + m * 16 + li;
        a[m] = *(const short8*)&Ab[row * 128 + (((kt * 4 + g) ^ (row & 7)) * 8)];
      }
#pragma unroll
      for (int n = 0; n < 4; ++n) {
        int row = wc * 64 + n * 16 + li;
        bf[n] = *(const short8*)&Bb[row * 128 + (((kt * 4 + g) ^ (row & 7)) * 8)];
      }
#pragma unroll
      for (int m = 0; m < 4; ++m)
#pragma unroll
        for (int n = 0; n < 4; ++n)
          acc[m][n] = MFMA(a[m], bf[n], acc[m][n]);
    }
  }
  __syncthreads();
#pragma unroll
  for (int n = 0; n < 4; ++n) {
    int col_l = wc * 64 + n * 16 + li;
#pragma unroll
    for (int m = 0; m < 4; ++m)
#pragma unroll
      for (int r = 0; r < 4; ++r) {
        int row_l = wr * 64 + m * 16 + g * 4 + r;
        Rp[row_l * 128 + (col_l ^ ((row_l & 7) << 2))] = acc[m][n][r];
      }
  }
  __syncthreads();
#pragma unroll
  for (int it = 0; it < 16; ++it) {
    int gi = it * 256 + tid, row = gi >> 5, ch = gi & 31;
    float4 dv = *(const float4*)&Rp[row * 128 + ((ch ^ (row & 7)) * 4)];
    float4 rv = *(const float4*)(out + (rowbase + row) * 128 + ch * 4);
    float4 bv = *(const float4*)(fb + ch * 4);
    float4 ov;
    ov.x = dv.x + rv.x + bv.x;
    ov.y = dv.y + rv.y + bv.y;
    ov.z = dv.z + rv.z + bv.z;
    ov.w = dv.w + rv.w + bv.w;
    *(float4*)(out + (rowbase + row) * 128 + ch * 4) = ov;
  }
}

// ---------------------------------------------------------------------------
extern "C" void kernel_launch(void* const* d_in, const int* in_sizes, int n_in,
                              void* d_out, int out_size, void* d_ws, size_t ws_size,
                              hipStream_t stream)
{
  const float* x      = (const float*)d_in[0];
  const float* g1     = (const float*)d_in[1];
  const float* b1     = (const float*)d_in[2];
  const float* qkv_w  = (const float*)d_in[3];
  const float* qkv_b  = (const float*)d_in[4];
  const float* rpb    = (const float*)d_in[5];
  const float* proj_w = (const float*)d_in[6];
  const float* proj_b = (const float*)d_in[7];
  const float* g2     = (const float*)d_in[8];
  const float* b2     = (const float*)d_in[9];
  const float* fc1_w  = (const float*)d_in[10];
  const float* fc1_b  = (const float*)d_in[11];
  const float* fc2_w  = (const float*)d_in[12];
  const float* fc2_b  = (const float*)d_in[13];

  char* ws = (char*)d_ws;
  float*  T       = (float*)ws;                 // 262144 B
  ushort* qkv_wb  = (ushort*)(ws + 262144);     // 98304
  ushort* proj_wb = (ushort*)(ws + 360448);     // 32768
  ushort* fc1_wb  = (ushort*)(ws + 393216);     // 131072
  ushort* fc2_wb  = (ushort*)(ws + 524288);     // 131072
  float*  qkv_bs  = (float*)(ws + 655360);      // 1536
  ushort* hid     = (ushort*)(ws + 656896);     // 205520896
  float* out = (float*)d_out;                   // x_new lives here too

  prep_kernel<<<256, 256, 0, stream>>>(qkv_w, qkv_b, rpb, proj_w, fc1_w, fc2_w,
                                       qkv_wb, qkv_bs, proj_wb, fc1_wb, fc2_wb, T);
  attn_kernel<<<4096, 256, 0, stream>>>(x, g1, b1, qkv_wb, qkv_bs, T,
                                        proj_wb, proj_b, out);
  fc1_kernel<<<dim3(4, 1568), 256, 0, stream>>>(out, g2, b2, fc1_wb, fc1_b, hid);
  fc2_kernel<<<1568, 256, 0, stream>>>(hid, fc2_wb, fc2_b, out);
}

// Round 3
// 646.951 us; speedup vs baseline: 3.5364x; 1.2809x over previous
//
#include <hip/hip_runtime.h>

typedef unsigned int uint;
typedef unsigned short ushort;
using short8 = __attribute__((ext_vector_type(8))) short;
using f32x4  = __attribute__((ext_vector_type(4))) float;
using uint4v = __attribute__((ext_vector_type(4))) uint;

#define SCALE_ 0.17677669529663687f
#define MFMA(a,b,c) __builtin_amdgcn_mfma_f32_16x16x32_bf16(a,b,c,0,0,0)

__device__ inline ushort f2bf(float f){
  uint u = __float_as_uint(f);
  return (ushort)((u + 0x7fffu + ((u >> 16) & 1u)) >> 16);
}
__device__ inline uint pk2(float a, float b){
  return (uint)f2bf(a) | ((uint)f2bf(b) << 16);
}
__device__ inline float bf2f(ushort h){ return __uint_as_float(((uint)h) << 16); }

// ---------------------------------------------------------------------------
// prep: bf16 weights (SCALE folded into q), scaled qkv bias, bias+mask table
// T2[cls][h][tok][key] (fp32, 64x64 padded; pad = -30000 so padding self-masks).
// ---------------------------------------------------------------------------
__global__ __launch_bounds__(256) void prep_kernel(
    const float* __restrict__ qkv_w, const float* __restrict__ qkv_b,
    const float* __restrict__ rpb, const float* __restrict__ proj_w,
    const float* __restrict__ fc1_w, const float* __restrict__ fc2_w,
    ushort* __restrict__ qkv_wb, float* __restrict__ qkv_bs,
    ushort* __restrict__ proj_wb, ushort* __restrict__ fc1_wb,
    ushort* __restrict__ fc2_wb, float* __restrict__ T2)
{
  int i = blockIdx.x * 256 + threadIdx.x;           // 0..65535
  if (i < 49152) qkv_wb[i] = f2bf(qkv_w[i] * (i < 16384 ? SCALE_ : 1.f));
  if (i < 16384) proj_wb[i] = f2bf(proj_w[i]);
  if (i < 65536) { fc1_wb[i] = f2bf(fc1_w[i]); fc2_wb[i] = f2bf(fc2_w[i]); }
  if (i < 384)   qkv_bs[i] = qkv_b[i] * (i < 128 ? SCALE_ : 1.f);
  if (i < 65536) {
    int cls = i >> 14, h = (i >> 12) & 3, tok = (i >> 6) & 63, key = i & 63;
    float val = -30000.f;
    if (tok < 49 && key < 49) {
      int ri = tok / 7, ci = tok - ri * 7, rj = key / 7, cj = key - rj * 7;
      val = rpb[((ri - rj + 6) * 13 + (ci - cj + 6)) * 4 + h];
      int er = cls >> 1, ec = cls & 1;
      int regi = (er ? (ri < 4 ? 1 : 2) : 0) * 3 + (ec ? (ci < 4 ? 1 : 2) : 0);
      int regj = (er ? (rj < 4 ? 1 : 2) : 0) * 3 + (ec ? (cj < 4 ? 1 : 2) : 0);
      if (regi != regj) val -= 100.f;
    }
    T2[i] = val;
  }
}

// ---------------------------------------------------------------------------
// attn v3: register-LN + per-head wave ownership + swapped-operand MFMA so
// softmax/P stay in registers.  LDS 48 KB, 2 barriers, 3 blocks/CU.
// One block per window (4096 blocks), 256 threads (wave w = head w).
// ---------------------------------------------------------------------------
__global__ __launch_bounds__(256, 3) void attn_kernel(
    const float* __restrict__ x, const float* __restrict__ g1, const float* __restrict__ b1,
    const ushort* __restrict__ qkv_wb, const float* __restrict__ qkv_bs,
    const float* __restrict__ T2, const ushort* __restrict__ proj_wb,
    const float* __restrict__ proj_b, float* __restrict__ x_new)
{
  // per-wave scratch (12288 B each): q [4 chslot][64 tok][8ch] (4096 B),
  // k same, v [8 tokslot][32 ch][8tok] (4096 B).  oa[64][136] aliases base.
  __shared__ __align__(16) char smem[49152];
  const int tid = threadIdx.x;
  const int w = tid >> 6, lane = tid & 63;
  const int g = lane >> 4, li = lane & 15;
  const int blk = blockIdx.x;
  const int b = blk >> 6, wi = blk & 63;
  const int wr = wi >> 3, wc = wi & 7;
  const float* xb = x + (size_t)b * (3136 * 128);
  char* qls = smem + w * 12288;
  char* kls = qls + 4096;
  char* vls = qls + 8192;
  ushort* oa = (ushort*)smem;
  const f32x4 zf = {0.f, 0.f, 0.f, 0.f};

  // ---- token coords (token = m*16+li), element offsets into x ----
  uint xoff[4];
#pragma unroll
  for (int m = 0; m < 4; ++m) {
    int t = m * 16 + li;
    int tr = t / 7, tc = t - tr * 7;
    int rr = wr * 7 + tr + 3; rr -= (rr >= 56) ? 56 : 0;
    int cc = wc * 7 + tc + 3; cc -= (cc >= 56) ? 56 : 0;
    xoff[m] = (uint)((rr * 56 + cc) * 128 + g * 8);
  }

  // ---- LN1 stats (per wave, registers only) ----
  float mean[4], rsig[4];
#pragma unroll
  for (int m = 0; m < 4; ++m) {
    float s = 0.f, s2 = 0.f;
#pragma unroll
    for (int kt = 0; kt < 4; ++kt) {
      float4 a0 = *(const float4*)(xb + xoff[m] + kt * 32);
      float4 a1 = *(const float4*)(xb + xoff[m] + kt * 32 + 4);
      s  += a0.x + a0.y + a0.z + a0.w + a1.x + a1.y + a1.z + a1.w;
      s2 += a0.x*a0.x + a0.y*a0.y + a0.z*a0.z + a0.w*a0.w
          + a1.x*a1.x + a1.y*a1.y + a1.z*a1.z + a1.w*a1.w;
    }
    s  += __shfl_xor(s, 16);  s  += __shfl_xor(s, 32);
    s2 += __shfl_xor(s2, 16); s2 += __shfl_xor(s2, 32);
    mean[m] = s * 0.0078125f;
    rsig[m] = rsqrtf(s2 * 0.0078125f - mean[m] * mean[m] + 1e-5f);
  }

  // ---- QKV: q,k swapped (weights as A); v normal (tokens as A) ----
  f32x4 qacc[2][4], kacc[2][4], vacc[4][2];
#pragma unroll
  for (int cf = 0; cf < 2; ++cf)
#pragma unroll
    for (int m = 0; m < 4; ++m) { qacc[cf][m] = zf; kacc[cf][m] = zf; vacc[m][cf] = zf; }

#pragma unroll
  for (int kt = 0; kt < 4; ++kt) {
    float4 gg0 = *(const float4*)(g1 + kt * 32 + g * 8);
    float4 gg1 = *(const float4*)(g1 + kt * 32 + g * 8 + 4);
    float4 bb0 = *(const float4*)(b1 + kt * 32 + g * 8);
    float4 bb1 = *(const float4*)(b1 + kt * 32 + g * 8 + 4);
    short8 xf[4];
#pragma unroll
    for (int m = 0; m < 4; ++m) {
      float4 a0 = *(const float4*)(xb + xoff[m] + kt * 32);
      float4 a1 = *(const float4*)(xb + xoff[m] + kt * 32 + 4);
      float mn = mean[m], rs = rsig[m];
      uint4v u;
      u.x = pk2((a0.x - mn) * rs * gg0.x + bb0.x, (a0.y - mn) * rs * gg0.y + bb0.y);
      u.y = pk2((a0.z - mn) * rs * gg0.z + bb0.z, (a0.w - mn) * rs * gg0.w + bb0.w);
      u.z = pk2((a1.x - mn) * rs * gg1.x + bb1.x, (a1.y - mn) * rs * gg1.y + bb1.y);
      u.w = pk2((a1.z - mn) * rs * gg1.z + bb1.z, (a1.w - mn) * rs * gg1.w + bb1.w);
      xf[m] = __builtin_bit_cast(short8, u);
    }
    const int wofs = kt * 32 + g * 8;
#pragma unroll
    for (int cf = 0; cf < 2; ++cf) {
      short8 wq = *(const short8*)(qkv_wb + (size_t)(w * 32 + cf * 16 + li) * 128 + wofs);
#pragma unroll
      for (int m = 0; m < 4; ++m) qacc[cf][m] = MFMA(wq, xf[m], qacc[cf][m]);
    }
#pragma unroll
    for (int cf = 0; cf < 2; ++cf) {
      short8 wk = *(const short8*)(qkv_wb + (size_t)(128 + w * 32 + cf * 16 + li) * 128 + wofs);
#pragma unroll
      for (int m = 0; m < 4; ++m) kacc[cf][m] = MFMA(wk, xf[m], kacc[cf][m]);
    }
#pragma unroll
    for (int cf = 0; cf < 2; ++cf) {
      short8 wv = *(const short8*)(qkv_wb + (size_t)(256 + w * 32 + cf * 16 + li) * 128 + wofs);
#pragma unroll
      for (int m = 0; m < 4; ++m) vacc[m][cf] = MFMA(xf[m], wv, vacc[m][cf]);
    }
  }

  // ---- biases + per-wave LDS stores (subtiled, 8B-aligned, ~conflict-free) ----
#pragma unroll
  for (int cf = 0; cf < 2; ++cf) {
    f32x4 qb4 = *(const f32x4*)(qkv_bs + w * 32 + cf * 16 + g * 4);
    f32x4 kb4 = *(const f32x4*)(qkv_bs + 128 + w * 32 + cf * 16 + g * 4);
    float vb = qkv_bs[256 + w * 32 + cf * 16 + li];
    const int qkoff = (cf * 2 + (g >> 1)) * 1024 + (g & 1) * 8;
#pragma unroll
    for (int m = 0; m < 4; ++m) {
      f32x4 qv = qacc[cf][m] + qb4;
      uint2 qu; qu.x = pk2(qv[0], qv[1]); qu.y = pk2(qv[2], qv[3]);
      *(uint2*)(qls + qkoff + (m * 16 + li) * 16) = qu;
      f32x4 kv = kacc[cf][m] + kb4;
      uint2 ku; ku.x = pk2(kv[0], kv[1]); ku.y = pk2(kv[2], kv[3]);
      *(uint2*)(kls + qkoff + (m * 16 + li) * 16) = ku;
      f32x4 vv = vacc[m][cf];
      uint2 vu; vu.x = pk2(vv[0] + vb, vv[1] + vb); vu.y = pk2(vv[2] + vb, vv[3] + vb);
      *(uint2*)(vls + (m * 2 + (g >> 1)) * 1024 + (cf * 16 + li) * 16 + (g & 1) * 8) = vu;
    }
  }

  // ---- scores (swapped: D[key][tok]) + in-register softmax + PV ----
  f32x4 oacc[2][4];
  {
    const int cls = ((wr == 7) ? 2 : 0) | ((wc == 7) ? 1 : 0);
    const float* Tb = T2 + ((cls * 4 + w) << 12);
    short8 kf[4];
#pragma unroll
    for (int n = 0; n < 4; ++n)
      kf[n] = *(const short8*)(kls + g * 1024 + (n * 16 + li) * 16);
    uint up[4][4][2];
#pragma unroll
    for (int m = 0; m < 4; ++m) {
      short8 qf = *(const short8*)(qls + g * 1024 + (m * 16 + li) * 16);
      f32x4 s[4];
#pragma unroll
      for (int n = 0; n < 4; ++n) {
        s[n] = MFMA(kf[n], qf, zf);
        s[n] += *(const f32x4*)(Tb + (m * 16 + li) * 64 + n * 16 + g * 4);
      }
      float mx = -3.4e38f;
#pragma unroll
      for (int n = 0; n < 4; ++n)
        mx = fmaxf(mx, fmaxf(fmaxf(s[n][0], s[n][1]), fmaxf(s[n][2], s[n][3])));
      mx = fmaxf(mx, __shfl_xor(mx, 16));
      mx = fmaxf(mx, __shfl_xor(mx, 32));
      float sum = 0.f;
#pragma unroll
      for (int n = 0; n < 4; ++n)
#pragma unroll
        for (int r = 0; r < 4; ++r) { float e = __expf(s[n][r] - mx); s[n][r] = e; sum += e; }
      sum += __shfl_xor(sum, 16); sum += __shfl_xor(sum, 32);
      float rs = 1.f / sum;
#pragma unroll
      for (int n = 0; n < 4; ++n) {
        up[m][n][0] = pk2(s[n][0] * rs, s[n][1] * rs);
        up[m][n][1] = pk2(s[n][2] * rs, s[n][3] * rs);
      }
    }
    // PV: P fragments built by 4-shfl lane redistribution (no LDS for P)
#pragma unroll
    for (int cf = 0; cf < 2; ++cf)
#pragma unroll
      for (int m = 0; m < 4; ++m) oacc[cf][m] = zf;
    const int srcA = ((g & 1) << 5) + li;
    const int hi = g >> 1;
#pragma unroll
    for (int kt = 0; kt < 2; ++kt) {
      short8 vt0 = *(const short8*)(vls + (kt * 4 + g) * 1024 + li * 16);
      short8 vt1 = *(const short8*)(vls + (kt * 4 + g) * 1024 + (16 + li) * 16);
#pragma unroll
      for (int m = 0; m < 4; ++m) {
        uint t00 = __shfl(up[m][kt * 2][0], srcA),      t10 = __shfl(up[m][kt * 2 + 1][0], srcA);
        uint t01 = __shfl(up[m][kt * 2][1], srcA),      t11 = __shfl(up[m][kt * 2 + 1][1], srcA);
        uint t02 = __shfl(up[m][kt * 2][0], srcA + 16), t12 = __shfl(up[m][kt * 2 + 1][0], srcA + 16);
        uint t03 = __shfl(up[m][kt * 2][1], srcA + 16), t13 = __shfl(up[m][kt * 2 + 1][1], srcA + 16);
        uint4v pu = { hi ? t10 : t00, hi ? t11 : t01, hi ? t12 : t02, hi ? t13 : t03 };
        short8 pf = __builtin_bit_cast(short8, pu);
        oacc[0][m] = MFMA(vt0, pf, oacc[0][m]);
        oacc[1][m] = MFMA(vt1, pf, oacc[1][m]);
      }
    }
  }
  __syncthreads();   // all waves done with per-wave scratch
  // attn-out -> shared oa[64][136] (bf16) for cross-wave proj
#pragma unroll
  for (int cf = 0; cf < 2; ++cf)
#pragma unroll
    for (int m = 0; m < 4; ++m) {
      uint2 ou; ou.x = pk2(oacc[cf][m][0], oacc[cf][m][1]);
      ou.y = pk2(oacc[cf][m][2], oacc[cf][m][3]);
      *(uint2*)((char*)oa + ((m * 16 + li) * 136 + w * 32 + cf * 16 + g * 4) * 2) = ou;
    }
  __syncthreads();

  // ---- proj + residual scatter (wave w owns out-ch [32w, 32w+32)) ----
  {
    f32x4 pacc[2][4];
#pragma unroll
    for (int cf = 0; cf < 2; ++cf)
#pragma unroll
      for (int m = 0; m < 4; ++m) pacc[cf][m] = zf;
#pragma unroll
    for (int kt = 0; kt < 4; ++kt) {
      short8 af[4];
#pragma unroll
      for (int m = 0; m < 4; ++m)
        af[m] = *(const short8*)((char*)oa + (m * 16 + li) * 272 + kt * 64 + g * 16);
#pragma unroll
      for (int cf = 0; cf < 2; ++cf) {
        short8 wp = *(const short8*)(proj_wb + (size_t)(w * 32 + cf * 16 + li) * 128 + kt * 32 + g * 8);
#pragma unroll
        for (int m = 0; m < 4; ++m) pacc[cf][m] = MFMA(af[m], wp, pacc[cf][m]);
      }
    }
#pragma unroll
    for (int cf = 0; cf < 2; ++cf) {
      int col = w * 32 + cf * 16 + li;
      float pb = proj_b[col];
#pragma unroll
      for (int m = 0; m < 4; ++m)
#pragma unroll
        for (int r = 0; r < 4; ++r) {
          int t2 = m * 16 + g * 4 + r;
          if (t2 < 49) {
            int tr2 = t2 / 7, tc2 = t2 - tr2 * 7;
            int rr = wr * 7 + tr2 + 3; rr -= (rr >= 56) ? 56 : 0;
            int cc = wc * 7 + tc2 + 3; cc -= (cc >= 56) ? 56 : 0;
            size_t off = ((size_t)b * 3136 + rr * 56 + cc) * 128 + col;
            x_new[off] = x[off] + pacc[cf][m][r] + pb;
          }
        }
    }
  }
}

// ---------------------------------------------------------------------------
// fc1: hid = gelu(LN2(x_new) @ fc1_w.T + b).  One block per 128-row stripe;
// A staged+LN'd ONCE, loop over 4 column tiles (B streams from L2).
// ---------------------------------------------------------------------------
__global__ __launch_bounds__(256) void fc1_kernel(
    const float* __restrict__ xn, const float* __restrict__ g2, const float* __restrict__ b2,
    const ushort* __restrict__ fw, const float* __restrict__ fb, ushort* __restrict__ hid)
{
  __shared__ __align__(16) ushort Ab[128 * 136];
  __shared__ __align__(16) ushort Bb[128 * 136];
  const int tid = threadIdx.x, lane = tid & 63, w = tid >> 6;
  const int g = lane >> 4, li = lane & 15;
  const size_t rowbase = (size_t)blockIdx.x * 128;

  { // A staging + fused LN2 (2 threads per row)
    int row = tid >> 1, hh = tid & 1;
    const float* src = xn + (rowbase + row) * 128 + hh * 64;
    float4 v[16];
    float s = 0.f, s2 = 0.f;
#pragma unroll
    for (int it = 0; it < 16; ++it) {
      v[it] = *(const float4*)(src + it * 4);
      s  += v[it].x + v[it].y + v[it].z + v[it].w;
      s2 += v[it].x * v[it].x + v[it].y * v[it].y + v[it].z * v[it].z + v[it].w * v[it].w;
    }
    s += __shfl_xor(s, 1); s2 += __shfl_xor(s2, 1);
    float mn = s * 0.0078125f;
    float rs = rsqrtf(s2 * 0.0078125f - mn * mn + 1e-5f);
#pragma unroll
    for (int c2 = 0; c2 < 8; ++c2) {
      int cb = hh * 64 + c2 * 8;
      float4 va = v[c2 * 2], vb2 = v[c2 * 2 + 1];
      float4 ga = *(const float4*)(g2 + cb), gb = *(const float4*)(g2 + cb + 4);
      float4 ba = *(const float4*)(b2 + cb), bb = *(const float4*)(b2 + cb + 4);
      uint4 pk;
      pk.x = pk2((va.x - mn) * rs * ga.x + ba.x, (va.y - mn) * rs * ga.y + ba.y);
      pk.y = pk2((va.z - mn) * rs * ga.z + ba.z, (va.w - mn) * rs * ga.w + ba.w);
      pk.z = pk2((vb2.x - mn) * rs * gb.x + bb.x, (vb2.y - mn) * rs * gb.y + bb.y);
      pk.w = pk2((vb2.z - mn) * rs * gb.z + bb.z, (vb2.w - mn) * rs * gb.w + bb.w);
      *(uint4*)&Ab[row * 136 + cb] = pk;
    }
  }
  const int wr = w >> 1, wc = w & 1;
  const f32x4 zf = {0.f, 0.f, 0.f, 0.f};

  for (int ct = 0; ct < 4; ++ct) {
#pragma unroll
    for (int it = 0; it < 8; ++it) {
      int gi = it * 256 + tid, row = gi >> 4, ch = gi & 15;
      *(uint4*)&Bb[row * 136 + ch * 8] =
          *(const uint4*)(fw + (size_t)(ct * 128 + row) * 128 + ch * 8);
    }
    __syncthreads();
    f32x4 acc[4][4];
#pragma unroll
    for (int m = 0; m < 4; ++m)
#pragma unroll
      for (int n = 0; n < 4; ++n) acc[m][n] = zf;
#pragma unroll
    for (int kt = 0; kt < 4; ++kt) {
      short8 a[4], bf[4];
#pragma unroll
      for (int m = 0; m < 4; ++m)
        a[m] = *(const short8*)&Ab[(wr * 64 + m * 16 + li) * 136 + kt * 32 + g * 8];
#pragma unroll
      for (int n = 0; n < 4; ++n)
        bf[n] = *(const short8*)&Bb[(wc * 64 + n * 16 + li) * 136 + kt * 32 + g * 8];
#pragma unroll
      for (int m = 0; m < 4; ++m)
#pragma unroll
        for (int n = 0; n < 4; ++n)
          acc[m][n] = MFMA(a[m], bf[n], acc[m][n]);
    }
    __syncthreads();
#pragma unroll
    for (int n = 0; n < 4; ++n) {
      int col_l = wc * 64 + n * 16 + li;
      float bias = fb[ct * 128 + col_l];
#pragma unroll
      for (int m = 0; m < 4; ++m)
#pragma unroll
        for (int r = 0; r < 4; ++r) {
          float vv = acc[m][n][r] + bias;
          vv = 0.5f * vv * (1.f + erff(vv * 0.70710678f));
          int row_l = wr * 64 + m * 16 + g * 4 + r;
          Bb[row_l * 136 + (col_l ^ ((row_l & 7) << 3))] = f2bf(vv);
        }
    }
    __syncthreads();
#pragma unroll
    for (int it = 0; it < 8; ++it) {
      int gi = it * 256 + tid, row = gi >> 4, ch = gi & 15;
      uint4 d = *(const uint4*)&Bb[row * 136 + ((ch ^ (row & 7)) * 8)];
      *(uint4*)&hid[(rowbase + row) * 512 + ct * 128 + ch * 8] = d;
    }
    __syncthreads();
  }
}

// ---------------------------------------------------------------------------
// fc2: out = x_new + hid @ fc2_w.T + b (in-place on d_out). 128x128 tile,
// K-loop of 4, bf16 MFMA, fp32 LDS repack for coalesced residual epilogue.
// ---------------------------------------------------------------------------
__global__ __launch_bounds__(256) void fc2_kernel(
    const ushort* __restrict__ hid, const ushort* __restrict__ fw,
    const float* __restrict__ fb, float* __restrict__ out)
{
  __shared__ __align__(16) char smem[65536];
  ushort* Ab = (ushort*)smem;
  ushort* Bb = (ushort*)(smem + 32768);
  float*  Rp = (float*)smem;
  const int tid = threadIdx.x, lane = tid & 63, w = tid >> 6;
  const int g = lane >> 4, li = lane & 15;
  const size_t rowbase = (size_t)blockIdx.x * 128;
  const int wr = w >> 1, wc = w & 1;

  f32x4 acc[4][4];
  const f32x4 zf = {0.f, 0.f, 0.f, 0.f};
#pragma unroll
  for (int m = 0; m < 4; ++m)
#pragma unroll
    for (int n = 0; n < 4; ++n) acc[m][n] = zf;

  for (int ck = 0; ck < 4; ++ck) {
    if (ck) __syncthreads();
#pragma unroll
    for (int it = 0; it < 8; ++it) {
      int gi = it * 256 + tid, row = gi >> 4, ch = gi & 15;
      uint4 d = *(const uint4*)(hid + (rowbase + row) * 512 + ck * 128 + ch * 8);
      *(uint4*)&Ab[row * 128 + ((ch ^ (row & 7)) * 8)] = d;
      uint4 e = *(const uint4*)(fw + (size_t)row * 512 + ck * 128 + ch * 8);
      *(uint4*)&Bb[row * 128 + ((ch ^ (row & 7)) * 8)] = e;
    }
    __syncthreads();
#pragma unroll
    for (int kt = 0; kt < 4; ++kt) {
      short8 a[4], bf[4];
#pragma unroll
      for (int m = 0; m < 4; ++m) {
        int row = wr * 64 + m * 16 + li;
        a[m] = *(const short8*)&Ab[row * 128 + (((kt * 4 + g) ^ (row & 7)) * 8)];
      }
#pragma unroll
      for (int n = 0; n < 4; ++n) {
        int row = wc * 64 + n * 16 + li;
        bf[n] = *(const short8*)&Bb[row * 128 + (((kt * 4 + g) ^ (row & 7)) * 8)];
      }
#pragma unroll
      for (int m = 0; m < 4; ++m)
#pragma unroll
        for (int n = 0; n < 4; ++n)
          acc[m][n] = MFMA(a[m], bf[n], acc[m][n]);
    }
  }
  __syncthreads();
#pragma unroll
  for (int n = 0; n < 4; ++n) {
    int col_l = wc * 64 + n * 16 + li;
#pragma unroll
    for (int m = 0; m < 4; ++m)
#pragma unroll
      for (int r = 0; r < 4; ++r) {
        int row_l = wr * 64 + m * 16 + g * 4 + r;
        Rp[row_l * 128 + (col_l ^ ((row_l & 7) << 2))] = acc[m][n][r];
      }
  }
  __syncthreads();
#pragma unroll
  for (int it = 0; it < 16; ++it) {
    int gi = it * 256 + tid, row = gi >> 5, ch = gi & 31;
    float4 dv = *(const float4*)&Rp[row * 128 + ((ch ^ (row & 7)) * 4)];
    float4 rv = *(const float4*)(out + (rowbase + row) * 128 + ch * 4);
    float4 bv = *(const float4*)(fb + ch * 4);
    float4 ov;
    ov.x = dv.x + rv.x + bv.x;
    ov.y = dv.y + rv.y + bv.y;
    ov.z = dv.z + rv.z + bv.z;
    ov.w = dv.w + rv.w + bv.w;
    *(float4*)(out + (rowbase + row) * 128 + ch * 4) = ov;
  }
}

// ---------------------------------------------------------------------------
extern "C" void kernel_launch(void* const* d_in, const int* in_sizes, int n_in,
                              void* d_out, int out_size, void* d_ws, size_t ws_size,
                              hipStream_t stream)
{
  const float* x      = (const float*)d_in[0];
  const float* g1     = (const float*)d_in[1];
  const float* b1     = (const float*)d_in[2];
  const float* qkv_w  = (const float*)d_in[3];
  const float* qkv_b  = (const float*)d_in[4];
  const float* rpb    = (const float*)d_in[5];
  const float* proj_w = (const float*)d_in[6];
  const float* proj_b = (const float*)d_in[7];
  const float* g2     = (const float*)d_in[8];
  const float* b2     = (const float*)d_in[9];
  const float* fc1_w  = (const float*)d_in[10];
  const float* fc1_b  = (const float*)d_in[11];
  const float* fc2_w  = (const float*)d_in[12];
  const float* fc2_b  = (const float*)d_in[13];

  char* ws = (char*)d_ws;
  float*  T2      = (float*)ws;                 // 262144 B
  ushort* qkv_wb  = (ushort*)(ws + 262144);     // 98304
  ushort* proj_wb = (ushort*)(ws + 360448);     // 32768
  ushort* fc1_wb  = (ushort*)(ws + 393216);     // 131072
  ushort* fc2_wb  = (ushort*)(ws + 524288);     // 131072
  float*  qkv_bs  = (float*)(ws + 655360);      // 1536
  ushort* hid     = (ushort*)(ws + 656896);     // 205520896
  float* out = (float*)d_out;                   // x_new lives here too

  prep_kernel<<<256, 256, 0, stream>>>(qkv_w, qkv_b, rpb, proj_w, fc1_w, fc2_w,
                                       qkv_wb, qkv_bs, proj_wb, fc1_wb, fc2_wb, T2);
  attn_kernel<<<4096, 256, 0, stream>>>(x, g1, b1, qkv_wb, qkv_bs, T2,
                                        proj_wb, proj_b, out);
  fc1_kernel<<<1568, 256, 0, stream>>>(out, g2, b2, fc1_wb, fc1_b, hid);
  fc2_kernel<<<1568, 256, 0, stream>>>(hid, fc2_wb, fc2_b, out);
}

// Round 4
// 526.608 us; speedup vs baseline: 4.3445x; 1.2285x over previous
//
#include <hip/hip_runtime.h>

typedef unsigned int uint;
typedef unsigned short ushort;
using short8 = __attribute__((ext_vector_type(8))) short;
using f32x4  = __attribute__((ext_vector_type(4))) float;
using uint4v = __attribute__((ext_vector_type(4))) uint;

#define SCALE_ 0.17677669529663687f
#define MFMA(a,b,c) __builtin_amdgcn_mfma_f32_16x16x32_bf16(a,b,c,0,0,0)

__device__ inline ushort f2bf(float f){
  uint u = __float_as_uint(f);
  return (ushort)((u + 0x7fffu + ((u >> 16) & 1u)) >> 16);
}
__device__ inline uint pk2(float a, float b){
  return (uint)f2bf(a) | ((uint)f2bf(b) << 16);
}
__device__ inline float gelu(float v){
  return 0.5f * v * (1.f + erff(v * 0.70710678f));
}

// ---------------------------------------------------------------------------
// prep: bf16 weights (SCALE folded into q), scaled qkv bias, bias+mask table
// T2[cls][h][tok][key] (fp32, 64x64 padded; pad = -30000 so padding self-masks).
// ---------------------------------------------------------------------------
__global__ __launch_bounds__(256) void prep_kernel(
    const float* __restrict__ qkv_w, const float* __restrict__ qkv_b,
    const float* __restrict__ rpb, const float* __restrict__ proj_w,
    const float* __restrict__ fc1_w, const float* __restrict__ fc2_w,
    ushort* __restrict__ qkv_wb, float* __restrict__ qkv_bs,
    ushort* __restrict__ proj_wb, ushort* __restrict__ fc1_wb,
    ushort* __restrict__ fc2_wb, float* __restrict__ T2)
{
  int i = blockIdx.x * 256 + threadIdx.x;           // 0..65535
  if (i < 49152) qkv_wb[i] = f2bf(qkv_w[i] * (i < 16384 ? SCALE_ : 1.f));
  if (i < 16384) proj_wb[i] = f2bf(proj_w[i]);
  if (i < 65536) { fc1_wb[i] = f2bf(fc1_w[i]); fc2_wb[i] = f2bf(fc2_w[i]); }
  if (i < 384)   qkv_bs[i] = qkv_b[i] * (i < 128 ? SCALE_ : 1.f);
  if (i < 65536) {
    int cls = i >> 14, h = (i >> 12) & 3, tok = (i >> 6) & 63, key = i & 63;
    float val = -30000.f;
    if (tok < 49 && key < 49) {
      int ri = tok / 7, ci = tok - ri * 7, rj = key / 7, cj = key - rj * 7;
      val = rpb[((ri - rj + 6) * 13 + (ci - cj + 6)) * 4 + h];
      int er = cls >> 1, ec = cls & 1;
      int regi = (er ? (ri < 4 ? 1 : 2) : 0) * 3 + (ec ? (ci < 4 ? 1 : 2) : 0);
      int regj = (er ? (rj < 4 ? 1 : 2) : 0) * 3 + (ec ? (cj < 4 ? 1 : 2) : 0);
      if (regi != regj) val -= 100.f;
    }
    T2[i] = val;
  }
}

// ---------------------------------------------------------------------------
// attn v4: coalesced LN1-staged LDS x-tile + per-head wave MFMA attention +
// in-register softmax + LDS-repacked coalesced residual epilogue.
// LDS 48 KB, 3 blocks/CU, one block per window (4096 blocks), 256 threads.
// ---------------------------------------------------------------------------
__global__ __launch_bounds__(256, 3) void attn_kernel(
    const float* __restrict__ x, const float* __restrict__ g1, const float* __restrict__ b1,
    const ushort* __restrict__ qkv_wb, const float* __restrict__ qkv_bs,
    const float* __restrict__ T2, const ushort* __restrict__ proj_wb,
    const float* __restrict__ proj_b, float* __restrict__ x_new)
{
  // layout: q [0,16K) per-wave 4K | k [16K,32K) per-wave 4K |
  //         xls [32K,48K) (subtiled bf16 LN1-x; aliased by per-wave v after B1)
  //         oa bf16[64][136] aliases [0,17408) after B2
  //         Rp fp32[49][128] (xor-swizzled) aliases [17408,42496) after B3
  __shared__ __align__(16) char smem[49152];
  const int tid = threadIdx.x;
  const int w = tid >> 6, lane = tid & 63;
  const int g = lane >> 4, li = lane & 15;
  const int blk = blockIdx.x;
  const int b = blk >> 6, wi = blk & 63;
  const int wr = wi >> 3, wc = wi & 7;
  const float* xb = x + (size_t)b * (3136 * 128);
  char* qls = smem + w * 4096;
  char* kls = smem + 16384 + w * 4096;
  char* vls = smem + 32768 + w * 4096;
  char* xls = smem + 32768;
  ushort* oa = (ushort*)smem;
  float* Rp = (float*)(smem + 17408);
  const f32x4 zf = {0.f, 0.f, 0.f, 0.f};

  // ---- P0: coalesced shifted gather + fp32 LN1 -> xls bf16 (swizzled) ----
#pragma unroll
  for (int it = 0; it < 7; ++it) {
    int gi = it * 256 + tid;
    bool ok = gi < 1568;
    int t = ok ? (gi >> 5) : 48;
    int ch4 = (gi & 31) << 2;
    int tr = t / 7, tc = t - tr * 7;
    int rr = wr * 7 + tr + 3; rr -= (rr >= 56) ? 56 : 0;
    int cc = wc * 7 + tc + 3; cc -= (cc >= 56) ? 56 : 0;
    float4 v = *(const float4*)(xb + (size_t)(rr * 56 + cc) * 128 + ch4);
    float s = v.x + v.y + v.z + v.w;
    float s2 = v.x*v.x + v.y*v.y + v.z*v.z + v.w*v.w;
#pragma unroll
    for (int off = 16; off; off >>= 1) { s += __shfl_xor(s, off); s2 += __shfl_xor(s2, off); }
    float mn = s * 0.0078125f;
    float rs = rsqrtf(s2 * 0.0078125f - mn * mn + 1e-5f);
    if (ok) {
      float4 gg = *(const float4*)(g1 + ch4);
      float4 bb = *(const float4*)(b1 + ch4);
      uint2 u;
      u.x = pk2((v.x - mn) * rs * gg.x + bb.x, (v.y - mn) * rs * gg.y + bb.y);
      u.y = pk2((v.z - mn) * rs * gg.z + bb.z, (v.w - mn) * rs * gg.w + bb.w);
      int slot = ch4 >> 3;
      int tokx = t ^ ((slot & 7) << 1);
      *(uint2*)(xls + (slot * 64 + tokx) * 16 + ((ch4 & 4) << 1)) = u;
    }
  }
  if (tid < 240) {   // zero pad tokens 49..63 (same swizzle -> bijective)
    int slot = tid & 15, t = 49 + (tid >> 4);
    int tokx = t ^ ((slot & 7) << 1);
    uint4 z = make_uint4(0u, 0u, 0u, 0u);
    *(uint4*)(xls + (slot * 64 + tokx) * 16) = z;
  }
  __syncthreads();                                  // B0: xls ready

  // ---- P1: QKV MFMA (q,k swapped: weights as A; v normal) ----
  f32x4 qacc[2][4], kacc[2][4], vacc[4][2];
#pragma unroll
  for (int cf = 0; cf < 2; ++cf)
#pragma unroll
    for (int m = 0; m < 4; ++m) { qacc[cf][m] = zf; kacc[cf][m] = zf; vacc[m][cf] = zf; }

#pragma unroll
  for (int kt = 0; kt < 4; ++kt) {
    const int slot = kt * 4 + g;
    short8 xf[4];
#pragma unroll
    for (int m = 0; m < 4; ++m)
      xf[m] = *(const short8*)(xls + (slot * 64 + ((m * 16 + li) ^ ((slot & 7) << 1))) * 16);
    const int wofs = kt * 32 + g * 8;
#pragma unroll
    for (int cf = 0; cf < 2; ++cf) {
      short8 wq = *(const short8*)(qkv_wb + (size_t)(w * 32 + cf * 16 + li) * 128 + wofs);
#pragma unroll
      for (int m = 0; m < 4; ++m) qacc[cf][m] = MFMA(wq, xf[m], qacc[cf][m]);
    }
#pragma unroll
    for (int cf = 0; cf < 2; ++cf) {
      short8 wk = *(const short8*)(qkv_wb + (size_t)(128 + w * 32 + cf * 16 + li) * 128 + wofs);
#pragma unroll
      for (int m = 0; m < 4; ++m) kacc[cf][m] = MFMA(wk, xf[m], kacc[cf][m]);
    }
#pragma unroll
    for (int cf = 0; cf < 2; ++cf) {
      short8 wv = *(const short8*)(qkv_wb + (size_t)(256 + w * 32 + cf * 16 + li) * 128 + wofs);
#pragma unroll
      for (int m = 0; m < 4; ++m) vacc[m][cf] = MFMA(xf[m], wv, vacc[m][cf]);
    }
  }
  // q,k + bias -> own-wave LDS (no cross-wave dep)
#pragma unroll
  for (int cf = 0; cf < 2; ++cf) {
    f32x4 qb4 = *(const f32x4*)(qkv_bs + w * 32 + cf * 16 + g * 4);
    f32x4 kb4 = *(const f32x4*)(qkv_bs + 128 + w * 32 + cf * 16 + g * 4);
    const int qkoff = (cf * 2 + (g >> 1)) * 1024 + (g & 1) * 8;
#pragma unroll
    for (int m = 0; m < 4; ++m) {
      f32x4 qv = qacc[cf][m] + qb4;
      uint2 qu; qu.x = pk2(qv[0], qv[1]); qu.y = pk2(qv[2], qv[3]);
      *(uint2*)(qls + qkoff + (m * 16 + li) * 16) = qu;
      f32x4 kv = kacc[cf][m] + kb4;
      uint2 ku; ku.x = pk2(kv[0], kv[1]); ku.y = pk2(kv[2], kv[3]);
      *(uint2*)(kls + qkoff + (m * 16 + li) * 16) = ku;
    }
  }
  __syncthreads();                                  // B1: all waves done with xls
#pragma unroll
  for (int cf = 0; cf < 2; ++cf) {
    float vb = qkv_bs[256 + w * 32 + cf * 16 + li];
#pragma unroll
    for (int m = 0; m < 4; ++m) {
      f32x4 vv = vacc[m][cf];
      uint2 vu; vu.x = pk2(vv[0] + vb, vv[1] + vb); vu.y = pk2(vv[2] + vb, vv[3] + vb);
      *(uint2*)(vls + (m * 2 + (g >> 1)) * 1024 + (cf * 16 + li) * 16 + (g & 1) * 8) = vu;
    }
  }

  // ---- P2: scores (D[key][tok]) + in-register softmax + PV ----
  f32x4 oacc[2][4];
  {
    const int cls = ((wr == 7) ? 2 : 0) | ((wc == 7) ? 1 : 0);
    const float* Tb = T2 + ((cls * 4 + w) << 12);
    short8 kf[4];
#pragma unroll
    for (int n = 0; n < 4; ++n)
      kf[n] = *(const short8*)(kls + g * 1024 + (n * 16 + li) * 16);
    uint up[4][4][2];
#pragma unroll
    for (int m = 0; m < 4; ++m) {
      short8 qf = *(const short8*)(qls + g * 1024 + (m * 16 + li) * 16);
      f32x4 s[4];
#pragma unroll
      for (int n = 0; n < 4; ++n) {
        s[n] = MFMA(kf[n], qf, zf);
        s[n] += *(const f32x4*)(Tb + (m * 16 + li) * 64 + n * 16 + g * 4);
      }
      float mx = -3.4e38f;
#pragma unroll
      for (int n = 0; n < 4; ++n)
        mx = fmaxf(mx, fmaxf(fmaxf(s[n][0], s[n][1]), fmaxf(s[n][2], s[n][3])));
      mx = fmaxf(mx, __shfl_xor(mx, 16));
      mx = fmaxf(mx, __shfl_xor(mx, 32));
      float sum = 0.f;
#pragma unroll
      for (int n = 0; n < 4; ++n)
#pragma unroll
        for (int r = 0; r < 4; ++r) { float e = __expf(s[n][r] - mx); s[n][r] = e; sum += e; }
      sum += __shfl_xor(sum, 16); sum += __shfl_xor(sum, 32);
      float rsm = 1.f / sum;
#pragma unroll
      for (int n = 0; n < 4; ++n) {
        up[m][n][0] = pk2(s[n][0] * rsm, s[n][1] * rsm);
        up[m][n][1] = pk2(s[n][2] * rsm, s[n][3] * rsm);
      }
    }
    // PV: P fragments via 4-shfl lane redistribution (no LDS for P)
#pragma unroll
    for (int cf = 0; cf < 2; ++cf)
#pragma unroll
      for (int m = 0; m < 4; ++m) oacc[cf][m] = zf;
    const int srcA = ((g & 1) << 5) + li;
    const int hi = g >> 1;
#pragma unroll
    for (int kt = 0; kt < 2; ++kt) {
      short8 vt0 = *(const short8*)(vls + (kt * 4 + g) * 1024 + li * 16);
      short8 vt1 = *(const short8*)(vls + (kt * 4 + g) * 1024 + (16 + li) * 16);
#pragma unroll
      for (int m = 0; m < 4; ++m) {
        uint t00 = __shfl(up[m][kt * 2][0], srcA),      t10 = __shfl(up[m][kt * 2 + 1][0], srcA);
        uint t01 = __shfl(up[m][kt * 2][1], srcA),      t11 = __shfl(up[m][kt * 2 + 1][1], srcA);
        uint t02 = __shfl(up[m][kt * 2][0], srcA + 16), t12 = __shfl(up[m][kt * 2 + 1][0], srcA + 16);
        uint t03 = __shfl(up[m][kt * 2][1], srcA + 16), t13 = __shfl(up[m][kt * 2 + 1][1], srcA + 16);
        uint4v pu = { hi ? t10 : t00, hi ? t11 : t01, hi ? t12 : t02, hi ? t13 : t03 };
        short8 pf = __builtin_bit_cast(short8, pu);
        oacc[0][m] = MFMA(vt0, pf, oacc[0][m]);
        oacc[1][m] = MFMA(vt1, pf, oacc[1][m]);
      }
    }
  }
  __syncthreads();                                  // B2: q/k/v scratch dead
#pragma unroll
  for (int cf = 0; cf < 2; ++cf)
#pragma unroll
    for (int m = 0; m < 4; ++m) {
      uint2 ou; ou.x = pk2(oacc[cf][m][0], oacc[cf][m][1]);
      ou.y = pk2(oacc[cf][m][2], oacc[cf][m][3]);
      *(uint2*)((char*)oa + ((m * 16 + li) * 136 + w * 32 + cf * 16 + g * 4) * 2) = ou;
    }
  __syncthreads();                                  // B3: oa ready

  // ---- P3: proj -> Rp (fp32, xor-swizzled) ----
  {
    f32x4 pacc[2][4];
#pragma unroll
    for (int cf = 0; cf < 2; ++cf)
#pragma unroll
      for (int m = 0; m < 4; ++m) pacc[cf][m] = zf;
#pragma unroll
    for (int kt = 0; kt < 4; ++kt) {
      short8 af[4];
#pragma unroll
      for (int m = 0; m < 4; ++m)
        af[m] = *(const short8*)((char*)oa + (m * 16 + li) * 272 + kt * 64 + g * 16);
#pragma unroll
      for (int cf = 0; cf < 2; ++cf) {
        short8 wp = *(const short8*)(proj_wb + (size_t)(w * 32 + cf * 16 + li) * 128 + kt * 32 + g * 8);
#pragma unroll
        for (int m = 0; m < 4; ++m) pacc[cf][m] = MFMA(af[m], wp, pacc[cf][m]);
      }
    }
#pragma unroll
    for (int cf = 0; cf < 2; ++cf) {
      int col = w * 32 + cf * 16 + li;
      float pb = proj_b[col];
#pragma unroll
      for (int m = 0; m < 4; ++m)
#pragma unroll
        for (int r = 0; r < 4; ++r) {
          int t2 = m * 16 + g * 4 + r;
          if (t2 < 49)
            Rp[t2 * 128 + (col ^ ((t2 & 7) << 2))] = pacc[cf][m][r] + pb;
        }
    }
  }
  __syncthreads();                                  // B4: Rp ready

  // ---- P4: coalesced residual epilogue ----
#pragma unroll
  for (int it = 0; it < 7; ++it) {
    int gi = it * 256 + tid;
    if (gi < 1568) {
      int t = gi >> 5, ch4 = (gi & 31) << 2;
      int tr = t / 7, tc = t - tr * 7;
      int rr = wr * 7 + tr + 3; rr -= (rr >= 56) ? 56 : 0;
      int cc = wc * 7 + tc + 3; cc -= (cc >= 56) ? 56 : 0;
      size_t off = ((size_t)b * 3136 + rr * 56 + cc) * 128 + ch4;
      f32x4 d = *(const f32x4*)&Rp[t * 128 + (ch4 ^ ((t & 7) << 2))];
      float4 xr = *(const float4*)(x + off);
      float4 ov;
      ov.x = xr.x + d[0]; ov.y = xr.y + d[1];
      ov.z = xr.z + d[2]; ov.w = xr.w + d[3];
      *(float4*)(x_new + off) = ov;
    }
  }
}

// ---------------------------------------------------------------------------
// fused MLP: xio = xio + fc2(gelu(fc1(LN2(xio)))), in place.  One block per
// 128-row stripe; each WAVE owns a private 32-row sub-stripe -> no barriers.
// hid never touches global memory (per-wave 8 KB LDS chunk, 4 chunks of 128).
// ---------------------------------------------------------------------------
__global__ __launch_bounds__(256, 2) void mlp_kernel(
    float* __restrict__ xio,
    const float* __restrict__ g2, const float* __restrict__ b2,
    const ushort* __restrict__ w1, const float* __restrict__ fb1,
    const ushort* __restrict__ w2, const float* __restrict__ fb2)
{
  __shared__ __align__(16) char smem[65536];   // per wave 16 KB: Axs 8K | hid 8K
  const int tid = threadIdx.x, lane = tid & 63, w = tid >> 6;
  const int g = lane >> 4, li = lane & 15;
  char* wbase = smem + w * 16384;
  char* hbase = wbase + 8192;
  float* xw = xio + ((size_t)blockIdx.x * 128 + w * 32) * 128;
  const f32x4 zf = {0.f, 0.f, 0.f, 0.f};

  // ---- stage: LN2(x) -> Axs bf16 [16 chslot][32 tok][16B], tok-xor swizzle --
#pragma unroll
  for (int it = 0; it < 16; ++it) {
    int gi = it * 64 + lane;
    int row = gi >> 5;                 // 0..31
    int ch4 = (gi & 31) << 2;
    float4 v = *(const float4*)(xw + row * 128 + ch4);
    float s = v.x + v.y + v.z + v.w;
    float s2 = v.x*v.x + v.y*v.y + v.z*v.z + v.w*v.w;
#pragma unroll
    for (int off = 16; off; off >>= 1) { s += __shfl_xor(s, off); s2 += __shfl_xor(s2, off); }
    float mn = s * 0.0078125f;
    float rs = rsqrtf(s2 * 0.0078125f - mn * mn + 1e-5f);
    float4 gg = *(const float4*)(g2 + ch4);
    float4 bb = *(const float4*)(b2 + ch4);
    uint2 u;
    u.x = pk2((v.x - mn) * rs * gg.x + bb.x, (v.y - mn) * rs * gg.y + bb.y);
    u.y = pk2((v.z - mn) * rs * gg.z + bb.z, (v.w - mn) * rs * gg.w + bb.w);
    int slot = ch4 >> 3;
    int tokx = row ^ ((slot & 7) << 1);
    *(uint2*)(wbase + (slot * 32 + tokx) * 16 + ((ch4 & 4) << 1)) = u;
  }

  f32x4 acc2[2][8];
#pragma unroll
  for (int mi = 0; mi < 2; ++mi)
#pragma unroll
    for (int bo = 0; bo < 8; ++bo) acc2[mi][bo] = zf;

  for (int ck = 0; ck < 4; ++ck) {
    // MFMA1: hid_chunk[och 128][tok 32] = W1[chunk] @ LN2(x)^T
    f32x4 acc1[8][2];
#pragma unroll
    for (int a = 0; a < 8; ++a) { acc1[a][0] = zf; acc1[a][1] = zf; }
#pragma unroll
    for (int kt = 0; kt < 4; ++kt) {
      const int slot = kt * 4 + g;
      short8 xf[2];
#pragma unroll
      for (int mi = 0; mi < 2; ++mi)
        xf[mi] = *(const short8*)(wbase + (slot * 32 + ((mi * 16 + li) ^ ((slot & 7) << 1))) * 16);
#pragma unroll
      for (int a = 0; a < 8; ++a) {
        short8 wf = *(const short8*)(w1 + (size_t)(ck * 128 + a * 16 + li) * 128 + kt * 32 + g * 8);
        acc1[a][0] = MFMA(wf, xf[0], acc1[a][0]);
        acc1[a][1] = MFMA(wf, xf[1], acc1[a][1]);
      }
    }
    // bias + GELU -> hid chunk LDS [16 ochslot][32 tok][16B] (och-major)
#pragma unroll
    for (int a = 0; a < 8; ++a) {
      f32x4 b4 = *(const f32x4*)(fb1 + ck * 128 + a * 16 + g * 4);
#pragma unroll
      for (int mi = 0; mi < 2; ++mi) {
        f32x4 h = acc1[a][mi] + b4;
        float h0 = gelu(h[0]), h1 = gelu(h[1]), h2 = gelu(h[2]), h3 = gelu(h[3]);
        uint2 u; u.x = pk2(h0, h1); u.y = pk2(h2, h3);
        *(uint2*)(hbase + ((a * 2 + (g >> 1)) * 32 + mi * 16 + li) * 16 + ((g & 1) << 3)) = u;
      }
    }
    // MFMA2: acc2[tok 32][out 128] += hid_chunk @ W2[chunk]^T
#pragma unroll
    for (int kt = 0; kt < 4; ++kt) {
      short8 hf[2];
#pragma unroll
      for (int mi = 0; mi < 2; ++mi)
        hf[mi] = *(const short8*)(hbase + ((kt * 4 + g) * 32 + mi * 16 + li) * 16);
#pragma unroll
      for (int bo = 0; bo < 8; ++bo) {
        short8 wf = *(const short8*)(w2 + (size_t)(bo * 16 + li) * 512 + ck * 128 + kt * 32 + g * 8);
        acc2[0][bo] = MFMA(hf[0], wf, acc2[0][bo]);
        acc2[1][bo] = MFMA(hf[1], wf, acc2[1][bo]);
      }
    }
  }

  // ---- epilogue: repack (xor-swizzled fp32 over dead Axs+hid) + residual ----
  float* rp = (float*)wbase;                  // [32][128]
#pragma unroll
  for (int mi = 0; mi < 2; ++mi)
#pragma unroll
    for (int bo = 0; bo < 8; ++bo) {
      int out = bo * 16 + li;
#pragma unroll
      for (int r = 0; r < 4; ++r) {
        int tok = mi * 16 + g * 4 + r;
        rp[tok * 128 + (out ^ ((tok & 7) << 2))] = acc2[mi][bo][r];
      }
    }
#pragma unroll
  for (int it = 0; it < 16; ++it) {
    int gi = it * 64 + lane;
    int row = gi >> 5, ch4 = (gi & 31) << 2;
    f32x4 d = *(const f32x4*)&rp[row * 128 + (ch4 ^ ((row & 7) << 2))];
    float4 xr = *(const float4*)(xw + row * 128 + ch4);
    float4 bb = *(const float4*)(fb2 + ch4);
    float4 ov;
    ov.x = xr.x + d[0] + bb.x; ov.y = xr.y + d[1] + bb.y;
    ov.z = xr.z + d[2] + bb.z; ov.w = xr.w + d[3] + bb.w;
    *(float4*)(xw + row * 128 + ch4) = ov;
  }
}

// ---------------------------------------------------------------------------
extern "C" void kernel_launch(void* const* d_in, const int* in_sizes, int n_in,
                              void* d_out, int out_size, void* d_ws, size_t ws_size,
                              hipStream_t stream)
{
  const float* x      = (const float*)d_in[0];
  const float* g1     = (const float*)d_in[1];
  const float* b1     = (const float*)d_in[2];
  const float* qkv_w  = (const float*)d_in[3];
  const float* qkv_b  = (const float*)d_in[4];
  const float* rpb    = (const float*)d_in[5];
  const float* proj_w = (const float*)d_in[6];
  const float* proj_b = (const float*)d_in[7];
  const float* g2     = (const float*)d_in[8];
  const float* b2     = (const float*)d_in[9];
  const float* fc1_w  = (const float*)d_in[10];
  const float* fc1_b  = (const float*)d_in[11];
  const float* fc2_w  = (const float*)d_in[12];
  const float* fc2_b  = (const float*)d_in[13];

  char* ws = (char*)d_ws;
  float*  T2      = (float*)ws;                 // 262144 B
  ushort* qkv_wb  = (ushort*)(ws + 262144);     // 98304
  ushort* proj_wb = (ushort*)(ws + 360448);     // 32768
  ushort* fc1_wb  = (ushort*)(ws + 393216);     // 131072
  ushort* fc2_wb  = (ushort*)(ws + 524288);     // 131072
  float*  qkv_bs  = (float*)(ws + 655360);      // 1536
  float* out = (float*)d_out;                   // x_new lives here too

  prep_kernel<<<256, 256, 0, stream>>>(qkv_w, qkv_b, rpb, proj_w, fc1_w, fc2_w,
                                       qkv_wb, qkv_bs, proj_wb, fc1_wb, fc2_wb, T2);
  attn_kernel<<<4096, 256, 0, stream>>>(x, g1, b1, qkv_wb, qkv_bs, T2,
                                        proj_wb, proj_b, out);
  mlp_kernel<<<1568, 256, 0, stream>>>(out, g2, b2, fc1_wb, fc1_b, fc2_wb, fc2_b);
}

// Round 5
// 356.853 us; speedup vs baseline: 6.4112x; 1.4757x over previous
//
#include <hip/hip_runtime.h>

typedef unsigned int uint;
typedef unsigned short ushort;
using short8 = __attribute__((ext_vector_type(8))) short;
using f32x4  = __attribute__((ext_vector_type(4))) float;
using uint4v = __attribute__((ext_vector_type(4))) uint;

#define SCALE_ 0.17677669529663687f
#define MFMA(a,b,c) __builtin_amdgcn_mfma_f32_16x16x32_bf16(a,b,c,0,0,0)

__device__ inline ushort f2bf(float f){
  uint u = __float_as_uint(f);
  return (ushort)((u + 0x7fffu + ((u >> 16) & 1u)) >> 16);
}
__device__ inline uint pk2(float a, float b){
  return (uint)f2bf(a) | ((uint)f2bf(b) << 16);
}
__device__ inline float gelu(float v){
  return 0.5f * v * (1.f + erff(v * 0.70710678f));
}

// ---------------------------------------------------------------------------
// prep: bf16 weights (SCALE folded into q), scaled qkv bias, bias+mask table
// T2[cls][h][tok][key] (fp32, 64x64 padded; pad = -30000 so padding self-masks).
// ---------------------------------------------------------------------------
__global__ __launch_bounds__(256) void prep_kernel(
    const float* __restrict__ qkv_w, const float* __restrict__ qkv_b,
    const float* __restrict__ rpb, const float* __restrict__ proj_w,
    const float* __restrict__ fc1_w, const float* __restrict__ fc2_w,
    ushort* __restrict__ qkv_wb, float* __restrict__ qkv_bs,
    ushort* __restrict__ proj_wb, ushort* __restrict__ fc1_wb,
    ushort* __restrict__ fc2_wb, float* __restrict__ T2)
{
  int i = blockIdx.x * 256 + threadIdx.x;           // 0..65535
  if (i < 49152) qkv_wb[i] = f2bf(qkv_w[i] * (i < 16384 ? SCALE_ : 1.f));
  if (i < 16384) proj_wb[i] = f2bf(proj_w[i]);
  if (i < 65536) { fc1_wb[i] = f2bf(fc1_w[i]); fc2_wb[i] = f2bf(fc2_w[i]); }
  if (i < 384)   qkv_bs[i] = qkv_b[i] * (i < 128 ? SCALE_ : 1.f);
  if (i < 65536) {
    int cls = i >> 14, h = (i >> 12) & 3, tok = (i >> 6) & 63, key = i & 63;
    float val = -30000.f;
    if (tok < 49 && key < 49) {
      int ri = tok / 7, ci = tok - ri * 7, rj = key / 7, cj = key - rj * 7;
      val = rpb[((ri - rj + 6) * 13 + (ci - cj + 6)) * 4 + h];
      int er = cls >> 1, ec = cls & 1;
      int regi = (er ? (ri < 4 ? 1 : 2) : 0) * 3 + (ec ? (ci < 4 ? 1 : 2) : 0);
      int regj = (er ? (rj < 4 ? 1 : 2) : 0) * 3 + (ec ? (cj < 4 ? 1 : 2) : 0);
      if (regi != regj) val -= 100.f;
    }
    T2[i] = val;
  }
}

// ---------------------------------------------------------------------------
// attn v4: coalesced LN1-staged LDS x-tile + per-head wave MFMA attention +
// in-register softmax + LDS-repacked coalesced residual epilogue.
// LDS 48 KB, 3 blocks/CU, one block per window (4096 blocks), 256 threads.
// ---------------------------------------------------------------------------
__global__ __launch_bounds__(256, 3) void attn_kernel(
    const float* __restrict__ x, const float* __restrict__ g1, const float* __restrict__ b1,
    const ushort* __restrict__ qkv_wb, const float* __restrict__ qkv_bs,
    const float* __restrict__ T2, const ushort* __restrict__ proj_wb,
    const float* __restrict__ proj_b, float* __restrict__ x_new)
{
  // layout: q [0,16K) per-wave 4K | k [16K,32K) per-wave 4K |
  //         xls [32K,48K) (subtiled bf16 LN1-x; aliased by per-wave v after B1)
  //         oa bf16[64][136] aliases [0,17408) after B2
  //         Rp fp32[49][128] (xor-swizzled) aliases [17408,42496) after B3
  __shared__ __align__(16) char smem[49152];
  const int tid = threadIdx.x;
  const int w = tid >> 6, lane = tid & 63;
  const int g = lane >> 4, li = lane & 15;
  const int blk = blockIdx.x;
  const int b = blk >> 6, wi = blk & 63;
  const int wr = wi >> 3, wc = wi & 7;
  const float* xb = x + (size_t)b * (3136 * 128);
  char* qls = smem + w * 4096;
  char* kls = smem + 16384 + w * 4096;
  char* vls = smem + 32768 + w * 4096;
  char* xls = smem + 32768;
  ushort* oa = (ushort*)smem;
  float* Rp = (float*)(smem + 17408);
  const f32x4 zf = {0.f, 0.f, 0.f, 0.f};

  // ---- P0: coalesced shifted gather + fp32 LN1 -> xls bf16 (swizzled) ----
#pragma unroll
  for (int it = 0; it < 7; ++it) {
    int gi = it * 256 + tid;
    bool ok = gi < 1568;
    int t = ok ? (gi >> 5) : 48;
    int ch4 = (gi & 31) << 2;
    int tr = t / 7, tc = t - tr * 7;
    int rr = wr * 7 + tr + 3; rr -= (rr >= 56) ? 56 : 0;
    int cc = wc * 7 + tc + 3; cc -= (cc >= 56) ? 56 : 0;
    float4 v = *(const float4*)(xb + (size_t)(rr * 56 + cc) * 128 + ch4);
    float s = v.x + v.y + v.z + v.w;
    float s2 = v.x*v.x + v.y*v.y + v.z*v.z + v.w*v.w;
#pragma unroll
    for (int off = 16; off; off >>= 1) { s += __shfl_xor(s, off); s2 += __shfl_xor(s2, off); }
    float mn = s * 0.0078125f;
    float rs = rsqrtf(s2 * 0.0078125f - mn * mn + 1e-5f);
    if (ok) {
      float4 gg = *(const float4*)(g1 + ch4);
      float4 bb = *(const float4*)(b1 + ch4);
      uint2 u;
      u.x = pk2((v.x - mn) * rs * gg.x + bb.x, (v.y - mn) * rs * gg.y + bb.y);
      u.y = pk2((v.z - mn) * rs * gg.z + bb.z, (v.w - mn) * rs * gg.w + bb.w);
      int slot = ch4 >> 3;
      int tokx = t ^ ((slot & 7) << 1);
      *(uint2*)(xls + (slot * 64 + tokx) * 16 + ((ch4 & 4) << 1)) = u;
    }
  }
  if (tid < 240) {   // zero pad tokens 49..63 (same swizzle -> bijective)
    int slot = tid & 15, t = 49 + (tid >> 4);
    int tokx = t ^ ((slot & 7) << 1);
    uint4 z = make_uint4(0u, 0u, 0u, 0u);
    *(uint4*)(xls + (slot * 64 + tokx) * 16) = z;
  }
  __syncthreads();                                  // B0: xls ready

  // ---- P1: QKV MFMA (q,k swapped: weights as A; v normal) ----
  f32x4 qacc[2][4], kacc[2][4], vacc[4][2];
#pragma unroll
  for (int cf = 0; cf < 2; ++cf)
#pragma unroll
    for (int m = 0; m < 4; ++m) { qacc[cf][m] = zf; kacc[cf][m] = zf; vacc[m][cf] = zf; }

#pragma unroll
  for (int kt = 0; kt < 4; ++kt) {
    const int slot = kt * 4 + g;
    short8 xf[4];
#pragma unroll
    for (int m = 0; m < 4; ++m)
      xf[m] = *(const short8*)(xls + (slot * 64 + ((m * 16 + li) ^ ((slot & 7) << 1))) * 16);
    const int wofs = kt * 32 + g * 8;
#pragma unroll
    for (int cf = 0; cf < 2; ++cf) {
      short8 wq = *(const short8*)(qkv_wb + (size_t)(w * 32 + cf * 16 + li) * 128 + wofs);
#pragma unroll
      for (int m = 0; m < 4; ++m) qacc[cf][m] = MFMA(wq, xf[m], qacc[cf][m]);
    }
#pragma unroll
    for (int cf = 0; cf < 2; ++cf) {
      short8 wk = *(const short8*)(qkv_wb + (size_t)(128 + w * 32 + cf * 16 + li) * 128 + wofs);
#pragma unroll
      for (int m = 0; m < 4; ++m) kacc[cf][m] = MFMA(wk, xf[m], kacc[cf][m]);
    }
#pragma unroll
    for (int cf = 0; cf < 2; ++cf) {
      short8 wv = *(const short8*)(qkv_wb + (size_t)(256 + w * 32 + cf * 16 + li) * 128 + wofs);
#pragma unroll
      for (int m = 0; m < 4; ++m) vacc[m][cf] = MFMA(xf[m], wv, vacc[m][cf]);
    }
  }
  // q,k + bias -> own-wave LDS (no cross-wave dep)
#pragma unroll
  for (int cf = 0; cf < 2; ++cf) {
    f32x4 qb4 = *(const f32x4*)(qkv_bs + w * 32 + cf * 16 + g * 4);
    f32x4 kb4 = *(const f32x4*)(qkv_bs + 128 + w * 32 + cf * 16 + g * 4);
    const int qkoff = (cf * 2 + (g >> 1)) * 1024 + (g & 1) * 8;
#pragma unroll
    for (int m = 0; m < 4; ++m) {
      f32x4 qv = qacc[cf][m] + qb4;
      uint2 qu; qu.x = pk2(qv[0], qv[1]); qu.y = pk2(qv[2], qv[3]);
      *(uint2*)(qls + qkoff + (m * 16 + li) * 16) = qu;
      f32x4 kv = kacc[cf][m] + kb4;
      uint2 ku; ku.x = pk2(kv[0], kv[1]); ku.y = pk2(kv[2], kv[3]);
      *(uint2*)(kls + qkoff + (m * 16 + li) * 16) = ku;
    }
  }
  __syncthreads();                                  // B1: all waves done with xls
#pragma unroll
  for (int cf = 0; cf < 2; ++cf) {
    float vb = qkv_bs[256 + w * 32 + cf * 16 + li];
#pragma unroll
    for (int m = 0; m < 4; ++m) {
      f32x4 vv = vacc[m][cf];
      uint2 vu; vu.x = pk2(vv[0] + vb, vv[1] + vb); vu.y = pk2(vv[2] + vb, vv[3] + vb);
      *(uint2*)(vls + (m * 2 + (g >> 1)) * 1024 + (cf * 16 + li) * 16 + (g & 1) * 8) = vu;
    }
  }

  // ---- P2: scores (D[key][tok]) + in-register softmax + PV ----
  f32x4 oacc[2][4];
  {
    const int cls = ((wr == 7) ? 2 : 0) | ((wc == 7) ? 1 : 0);
    const float* Tb = T2 + ((cls * 4 + w) << 12);
    short8 kf[4];
#pragma unroll
    for (int n = 0; n < 4; ++n)
      kf[n] = *(const short8*)(kls + g * 1024 + (n * 16 + li) * 16);
    uint up[4][4][2];
#pragma unroll
    for (int m = 0; m < 4; ++m) {
      short8 qf = *(const short8*)(qls + g * 1024 + (m * 16 + li) * 16);
      f32x4 s[4];
#pragma unroll
      for (int n = 0; n < 4; ++n) {
        s[n] = MFMA(kf[n], qf, zf);
        s[n] += *(const f32x4*)(Tb + (m * 16 + li) * 64 + n * 16 + g * 4);
      }
      float mx = -3.4e38f;
#pragma unroll
      for (int n = 0; n < 4; ++n)
        mx = fmaxf(mx, fmaxf(fmaxf(s[n][0], s[n][1]), fmaxf(s[n][2], s[n][3])));
      mx = fmaxf(mx, __shfl_xor(mx, 16));
      mx = fmaxf(mx, __shfl_xor(mx, 32));
      float sum = 0.f;
#pragma unroll
      for (int n = 0; n < 4; ++n)
#pragma unroll
        for (int r = 0; r < 4; ++r) { float e = __expf(s[n][r] - mx); s[n][r] = e; sum += e; }
      sum += __shfl_xor(sum, 16); sum += __shfl_xor(sum, 32);
      float rsm = 1.f / sum;
#pragma unroll
      for (int n = 0; n < 4; ++n) {
        up[m][n][0] = pk2(s[n][0] * rsm, s[n][1] * rsm);
        up[m][n][1] = pk2(s[n][2] * rsm, s[n][3] * rsm);
      }
    }
    // PV: P fragments via 4-shfl lane redistribution (no LDS for P)
#pragma unroll
    for (int cf = 0; cf < 2; ++cf)
#pragma unroll
      for (int m = 0; m < 4; ++m) oacc[cf][m] = zf;
    const int srcA = ((g & 1) << 5) + li;
    const int hi = g >> 1;
#pragma unroll
    for (int kt = 0; kt < 2; ++kt) {
      short8 vt0 = *(const short8*)(vls + (kt * 4 + g) * 1024 + li * 16);
      short8 vt1 = *(const short8*)(vls + (kt * 4 + g) * 1024 + (16 + li) * 16);
#pragma unroll
      for (int m = 0; m < 4; ++m) {
        uint t00 = __shfl(up[m][kt * 2][0], srcA),      t10 = __shfl(up[m][kt * 2 + 1][0], srcA);
        uint t01 = __shfl(up[m][kt * 2][1], srcA),      t11 = __shfl(up[m][kt * 2 + 1][1], srcA);
        uint t02 = __shfl(up[m][kt * 2][0], srcA + 16), t12 = __shfl(up[m][kt * 2 + 1][0], srcA + 16);
        uint t03 = __shfl(up[m][kt * 2][1], srcA + 16), t13 = __shfl(up[m][kt * 2 + 1][1], srcA + 16);
        uint4v pu = { hi ? t10 : t00, hi ? t11 : t01, hi ? t12 : t02, hi ? t13 : t03 };
        short8 pf = __builtin_bit_cast(short8, pu);
        oacc[0][m] = MFMA(vt0, pf, oacc[0][m]);
        oacc[1][m] = MFMA(vt1, pf, oacc[1][m]);
      }
    }
  }
  __syncthreads();                                  // B2: q/k/v scratch dead
#pragma unroll
  for (int cf = 0; cf < 2; ++cf)
#pragma unroll
    for (int m = 0; m < 4; ++m) {
      uint2 ou; ou.x = pk2(oacc[cf][m][0], oacc[cf][m][1]);
      ou.y = pk2(oacc[cf][m][2], oacc[cf][m][3]);
      *(uint2*)((char*)oa + ((m * 16 + li) * 136 + w * 32 + cf * 16 + g * 4) * 2) = ou;
    }
  __syncthreads();                                  // B3: oa ready

  // ---- P3: proj -> Rp (fp32, xor-swizzled) ----
  {
    f32x4 pacc[2][4];
#pragma unroll
    for (int cf = 0; cf < 2; ++cf)
#pragma unroll
      for (int m = 0; m < 4; ++m) pacc[cf][m] = zf;
#pragma unroll
    for (int kt = 0; kt < 4; ++kt) {
      short8 af[4];
#pragma unroll
      for (int m = 0; m < 4; ++m)
        af[m] = *(const short8*)((char*)oa + (m * 16 + li) * 272 + kt * 64 + g * 16);
#pragma unroll
      for (int cf = 0; cf < 2; ++cf) {
        short8 wp = *(const short8*)(proj_wb + (size_t)(w * 32 + cf * 16 + li) * 128 + kt * 32 + g * 8);
#pragma unroll
        for (int m = 0; m < 4; ++m) pacc[cf][m] = MFMA(af[m], wp, pacc[cf][m]);
      }
    }
#pragma unroll
    for (int cf = 0; cf < 2; ++cf) {
      int col = w * 32 + cf * 16 + li;
      float pb = proj_b[col];
#pragma unroll
      for (int m = 0; m < 4; ++m)
#pragma unroll
        for (int r = 0; r < 4; ++r) {
          int t2 = m * 16 + g * 4 + r;
          if (t2 < 49)
            Rp[t2 * 128 + (col ^ ((t2 & 7) << 2))] = pacc[cf][m][r] + pb;
        }
    }
  }
  __syncthreads();                                  // B4: Rp ready

  // ---- P4: coalesced residual epilogue ----
#pragma unroll
  for (int it = 0; it < 7; ++it) {
    int gi = it * 256 + tid;
    if (gi < 1568) {
      int t = gi >> 5, ch4 = (gi & 31) << 2;
      int tr = t / 7, tc = t - tr * 7;
      int rr = wr * 7 + tr + 3; rr -= (rr >= 56) ? 56 : 0;
      int cc = wc * 7 + tc + 3; cc -= (cc >= 56) ? 56 : 0;
      size_t off = ((size_t)b * 3136 + rr * 56 + cc) * 128 + ch4;
      f32x4 d = *(const f32x4*)&Rp[t * 128 + (ch4 ^ ((t & 7) << 2))];
      float4 xr = *(const float4*)(x + off);
      float4 ov;
      ov.x = xr.x + d[0]; ov.y = xr.y + d[1];
      ov.z = xr.z + d[2]; ov.w = xr.w + d[3];
      *(float4*)(x_new + off) = ov;
    }
  }
}

// ---------------------------------------------------------------------------
// fused MLP v2 (cooperative): block = 64 rows, 4 waves COOPERATE.
// Axs = LN2(x) bf16 (16 KB shared); per 128-och chunk: MFMA1 (waves split och)
// -> GELU -> hid chunk LDS (16 KB shared) -> MFMA2 (waves split out cols).
// LDS 32 KB -> 4 blocks/CU; weights read once per block (no per-wave dup).
// ---------------------------------------------------------------------------
__global__ __launch_bounds__(256, 4) void mlp_kernel(
    float* __restrict__ xio,
    const float* __restrict__ g2, const float* __restrict__ b2,
    const ushort* __restrict__ w1, const float* __restrict__ fb1,
    const ushort* __restrict__ w2, const float* __restrict__ fb2)
{
  __shared__ __align__(16) char smem[32768];   // Axs 16K | hid 16K; Rp aliases all
  char* Axs = smem;
  char* hls = smem + 16384;
  float* Rp = (float*)smem;
  const int tid = threadIdx.x, lane = tid & 63, w = tid >> 6;
  const int g = lane >> 4, li = lane & 15;
  float* xw = xio + (size_t)blockIdx.x * 64 * 128;
  const f32x4 zf = {0.f, 0.f, 0.f, 0.f};

  // ---- stage: LN2(x) -> Axs bf16 [16 chslot][64 tok][16B], tok-xor swizzle --
#pragma unroll
  for (int it = 0; it < 8; ++it) {
    int gi = it * 256 + tid;
    int row = gi >> 5, ch4 = (gi & 31) << 2;
    float4 v = *(const float4*)(xw + row * 128 + ch4);
    float s = v.x + v.y + v.z + v.w;
    float s2 = v.x*v.x + v.y*v.y + v.z*v.z + v.w*v.w;
#pragma unroll
    for (int off = 16; off; off >>= 1) { s += __shfl_xor(s, off); s2 += __shfl_xor(s2, off); }
    float mn = s * 0.0078125f;
    float rs = rsqrtf(s2 * 0.0078125f - mn * mn + 1e-5f);
    float4 gg = *(const float4*)(g2 + ch4);
    float4 bb = *(const float4*)(b2 + ch4);
    uint2 u;
    u.x = pk2((v.x - mn) * rs * gg.x + bb.x, (v.y - mn) * rs * gg.y + bb.y);
    u.y = pk2((v.z - mn) * rs * gg.z + bb.z, (v.w - mn) * rs * gg.w + bb.w);
    int slot = ch4 >> 3;
    int tokx = row ^ ((slot & 7) << 1);
    *(uint2*)(Axs + (slot * 64 + tokx) * 16 + ((ch4 & 4) << 1)) = u;
  }
  __syncthreads();

  f32x4 acc2[4][2];
#pragma unroll
  for (int mi = 0; mi < 4; ++mi) { acc2[mi][0] = zf; acc2[mi][1] = zf; }

  for (int ck = 0; ck < 4; ++ck) {
    // ---- MFMA1: hid_c[och 32 (this wave)][tok 64] = W1 slice @ LN2(x)^T ----
    f32x4 acc1[2][4];
#pragma unroll
    for (int oi = 0; oi < 2; ++oi)
#pragma unroll
      for (int mi = 0; mi < 4; ++mi) acc1[oi][mi] = zf;
#pragma unroll
    for (int kt = 0; kt < 4; ++kt) {
      const int slot = kt * 4 + g;
      short8 xf[4];
#pragma unroll
      for (int mi = 0; mi < 4; ++mi)
        xf[mi] = *(const short8*)(Axs + (slot * 64 + ((mi * 16 + li) ^ ((slot & 7) << 1))) * 16);
#pragma unroll
      for (int oi = 0; oi < 2; ++oi) {
        short8 wf = *(const short8*)(w1 + (size_t)(ck * 128 + w * 32 + oi * 16 + li) * 128 + kt * 32 + g * 8);
#pragma unroll
        for (int mi = 0; mi < 4; ++mi) acc1[oi][mi] = MFMA(wf, xf[mi], acc1[oi][mi]);
      }
    }
    // bias + GELU -> hid [16 ochslot][64 tok][16B]
#pragma unroll
    for (int oi = 0; oi < 2; ++oi) {
      f32x4 b4 = *(const f32x4*)(fb1 + ck * 128 + w * 32 + oi * 16 + g * 4);
#pragma unroll
      for (int mi = 0; mi < 4; ++mi) {
        f32x4 h = acc1[oi][mi] + b4;
        uint2 u; u.x = pk2(gelu(h[0]), gelu(h[1])); u.y = pk2(gelu(h[2]), gelu(h[3]));
        *(uint2*)(hls + ((w * 4 + oi * 2 + (g >> 1)) * 64 + mi * 16 + li) * 16 + ((g & 1) << 3)) = u;
      }
    }
    __syncthreads();                  // hid chunk ready
    // ---- MFMA2: acc2[tok 64][out 32 (this wave)] += hid_c @ W2 slice^T ----
#pragma unroll
    for (int kt = 0; kt < 4; ++kt) {
      short8 hf[4];
#pragma unroll
      for (int mi = 0; mi < 4; ++mi)
        hf[mi] = *(const short8*)(hls + ((kt * 4 + g) * 64 + mi * 16 + li) * 16);
#pragma unroll
      for (int bo = 0; bo < 2; ++bo) {
        short8 wf = *(const short8*)(w2 + (size_t)(w * 32 + bo * 16 + li) * 512 + ck * 128 + kt * 32 + g * 8);
#pragma unroll
        for (int mi = 0; mi < 4; ++mi) acc2[mi][bo] = MFMA(hf[mi], wf, acc2[mi][bo]);
      }
    }
    __syncthreads();                  // all reads done before next chunk's writes
  }

  // ---- epilogue: fp32 xor-swizzled repack over dead Axs+hid + residual ----
#pragma unroll
  for (int mi = 0; mi < 4; ++mi)
#pragma unroll
    for (int bo = 0; bo < 2; ++bo) {
      int out = w * 32 + bo * 16 + li;
#pragma unroll
      for (int r = 0; r < 4; ++r) {
        int tok = mi * 16 + g * 4 + r;
        Rp[tok * 128 + (out ^ ((tok & 7) << 2))] = acc2[mi][bo][r];
      }
    }
  __syncthreads();
#pragma unroll
  for (int it = 0; it < 8; ++it) {
    int gi = it * 256 + tid;
    int row = gi >> 5, ch4 = (gi & 31) << 2;
    f32x4 d = *(const f32x4*)&Rp[row * 128 + (ch4 ^ ((row & 7) << 2))];
    float4 xr = *(const float4*)(xw + row * 128 + ch4);
    float4 bb = *(const float4*)(fb2 + ch4);
    float4 ov;
    ov.x = xr.x + d[0] + bb.x; ov.y = xr.y + d[1] + bb.y;
    ov.z = xr.z + d[2] + bb.z; ov.w = xr.w + d[3] + bb.w;
    *(float4*)(xw + row * 128 + ch4) = ov;
  }
}

// ---------------------------------------------------------------------------
extern "C" void kernel_launch(void* const* d_in, const int* in_sizes, int n_in,
                              void* d_out, int out_size, void* d_ws, size_t ws_size,
                              hipStream_t stream)
{
  const float* x      = (const float*)d_in[0];
  const float* g1     = (const float*)d_in[1];
  const float* b1     = (const float*)d_in[2];
  const float* qkv_w  = (const float*)d_in[3];
  const float* qkv_b  = (const float*)d_in[4];
  const float* rpb    = (const float*)d_in[5];
  const float* proj_w = (const float*)d_in[6];
  const float* proj_b = (const float*)d_in[7];
  const float* g2     = (const float*)d_in[8];
  const float* b2     = (const float*)d_in[9];
  const float* fc1_w  = (const float*)d_in[10];
  const float* fc1_b  = (const float*)d_in[11];
  const float* fc2_w  = (const float*)d_in[12];
  const float* fc2_b  = (const float*)d_in[13];

  char* ws = (char*)d_ws;
  float*  T2      = (float*)ws;                 // 262144 B
  ushort* qkv_wb  = (ushort*)(ws + 262144);     // 98304
  ushort* proj_wb = (ushort*)(ws + 360448);     // 32768
  ushort* fc1_wb  = (ushort*)(ws + 393216);     // 131072
  ushort* fc2_wb  = (ushort*)(ws + 524288);     // 131072
  float*  qkv_bs  = (float*)(ws + 655360);      // 1536
  float* out = (float*)d_out;                   // x_new lives here too

  prep_kernel<<<256, 256, 0, stream>>>(qkv_w, qkv_b, rpb, proj_w, fc1_w, fc2_w,
                                       qkv_wb, qkv_bs, proj_wb, fc1_wb, fc2_wb, T2);
  attn_kernel<<<4096, 256, 0, stream>>>(x, g1, b1, qkv_wb, qkv_bs, T2,
                                        proj_wb, proj_b, out);
  mlp_kernel<<<3136, 256, 0, stream>>>(out, g2, b2, fc1_wb, fc1_b, fc2_wb, fc2_b);
}